// Round 17
// baseline (230.350 us; speedup 1.0000x reference)
//
#include <hip/hip_runtime.h>
#include <math.h>

#define B_ 8
#define C_ 64
#define H_ 256
#define W_ 256
#define WF 129
#define P_ (B_*C_)      // 512 planes
#define PI_F 3.14159265358979323846f
#define ZPAD 264        // row stride (4B units) == 8 mod 32 -> 2-way banks

typedef _Float16 f16;
struct h2 { f16 x, y; };          // 4 B
struct h4 { f16 x, y, z, w; };    // 8 B
typedef _Float16 f16x8 __attribute__((ext_vector_type(8)));
typedef float f32x4 __attribute__((ext_vector_type(4)));
typedef float cf __attribute__((ext_vector_type(2)));

__device__ __forceinline__ void stz(h2* p, cf v){ h2 o; o.x=(f16)v.x; o.y=(f16)v.y; *p=o; }
__device__ __forceinline__ cf   ldz(const h2* p){ h2 v=*p; return (cf){(float)v.x,(float)v.y}; }

__device__ __forceinline__ cf cmulv(cf a, cf w){
    cf m = a.yy * w.yx;
    cf ms = (cf){-m.x, m.y};
    return a.xx * w + ms;
}
// forward DFT4 butterfly (W4 = -i rotation)
__device__ __forceinline__ void bf4f(cf u0, cf u1, cf u2, cf u3,
                                     cf& y0, cf& y1, cf& y2, cf& y3){
    cf P = u0 + u2, M = u0 - u2;
    cf Q = u1 + u3, R = u1 - u3;
    cf Rr = (cf){R.y, -R.x};
    y0 = P + Q;  y2 = P - Q;
    y1 = M + Rr; y3 = M - Rr;
}
// inverse DFT4 butterfly (+i rotation)
__device__ __forceinline__ void bf4i(cf u0, cf u1, cf u2, cf u3,
                                     cf& y0, cf& y1, cf& y2, cf& y3){
    cf P = u0 + u2, M = u0 - u2;
    cf Q = u1 + u3, R = u1 - u3;
    cf Ri = (cf){-R.y, R.x};
    y0 = P + Q;  y2 = P - Q;
    y1 = M + Ri; y3 = M - Ri;
}

// full 16-point FFT in registers; radix-4 x 2, constant W16 twiddles.
template<bool INV>
__device__ __forceinline__ void fft16r(cf* a){
    const float C1 = 0.92387953251128674f;
    const float S1 = 0.38268343236508978f;
    const float R2 = 0.70710678118654752f;
    cf b[16];
    #pragma unroll
    for (int m0 = 0; m0 < 4; ++m0){
        cf y0,y1,y2,y3;
        if (!INV) bf4f(a[m0], a[m0+4], a[m0+8], a[m0+12], y0,y1,y2,y3);
        else      bf4i(a[m0], a[m0+4], a[m0+8], a[m0+12], y0,y1,y2,y3);
        b[m0*4+0]=y0; b[m0*4+1]=y1; b[m0*4+2]=y2; b[m0*4+3]=y3;
    }
    const float sg = INV ? 1.f : -1.f;
    b[5]  = cmulv(b[5],  (cf){C1,  sg*S1});
    b[6]  = cmulv(b[6],  (cf){R2,  sg*R2});
    b[7]  = cmulv(b[7],  (cf){S1,  sg*C1});
    b[9]  = cmulv(b[9],  (cf){R2,  sg*R2});
    b[10] = cmulv(b[10], (cf){0.f, sg*1.f});
    b[11] = cmulv(b[11], (cf){-R2, sg*R2});
    b[13] = cmulv(b[13], (cf){S1,  sg*C1});
    b[14] = cmulv(b[14], (cf){-R2, sg*R2});
    b[15] = cmulv(b[15], (cf){-C1, -sg*S1});
    #pragma unroll
    for (int r0 = 0; r0 < 4; ++r0){
        cf y0,y1,y2,y3;
        if (!INV) bf4f(b[r0], b[4+r0], b[8+r0], b[12+r0], y0,y1,y2,y3);
        else      bf4i(b[r0], b[4+r0], b[8+r0], b[12+r0], y0,y1,y2,y3);
        a[r0]    = y0;
        a[r0+4]  = y1;
        a[r0+8]  = y2;
        a[r0+12] = y3;
    }
}

// outer twiddle chain: a[k] *= W256^{±lo*k}
template<bool INV>
__device__ __forceinline__ void twchain(cf* a, int lo){
    float ang = (INV ? 2.f : -2.f) * PI_F * (float)lo / 256.f;
    cf wst = (cf){__cosf(ang), __sinf(ang)};
    cf w = (cf){1.f, 0.f};
    #pragma unroll
    for (int k = 1; k < 16; ++k){ w = cmulv(w, wst); a[k] = cmulv(a[k], w); }
}

// ---------------------------------------------------------------------------
// K1: row rfft (two-for-one), 16x16 register FFT, f16 LDS transposes.
// grid (P_, H_/32), block 256. Writes S as h4 pairs, folds ortho 1/256.
// ---------------------------------------------------------------------------
__global__ void __launch_bounds__(256) k1_row_rfft(const float* __restrict__ x,
                                                   h2* __restrict__ S){
    __shared__ h2 zc[16][ZPAD];   // 16.9 KB

    const int p = blockIdx.x, tile = blockIdx.y, t = threadIdx.x;
    const int h0 = tile * 32;
    const float* xp = x + (size_t)p*H_*W_ + (size_t)h0*W_;

    #pragma unroll
    for (int q = 0; q < 16; ++q)
        stz(&zc[q][t], (cf){xp[(2*q)*W_ + t], xp[(2*q+1)*W_ + t]});
    __syncthreads();

    const int q = t >> 4, lo = t & 15;
    cf a[16];
    // P1: FFT16 over n1, outer twiddle, transposed write (s(a)=a swizzle)
    #pragma unroll
    for (int n1 = 0; n1 < 16; ++n1) a[n1] = ldz(&zc[q][lo + 16*n1]);
    fft16r<false>(a);
    twchain<false>(a, lo);
    __syncthreads();
    #pragma unroll
    for (int k0 = 0; k0 < 16; ++k0) stz(&zc[q][16*lo + (k0 ^ lo)], a[k0]);
    __syncthreads();
    // P2: FFT16 over n0 -> Z[lo + 16k1]
    #pragma unroll
    for (int n0 = 0; n0 < 16; ++n0) a[n0] = ldz(&zc[q][16*n0 + (lo ^ n0)]);
    fft16r<false>(a);
    __syncthreads();
    #pragma unroll
    for (int k1 = 0; k1 < 16; ++k1) stz(&zc[q][lo + 16*k1], a[k1]);  // natural
    __syncthreads();

    const float sc = 0.5f / 256.f;
    h2* Sp = S + (size_t)p*WF*H_;
    for (int idx = t; idx < WF*16; idx += 256){
        int kw = idx >> 4, qq = idx & 15;
        cf Z = ldz(&zc[qq][kw]);
        cf Y = ldz(&zc[qq][(256-kw)&255]);
        h4 o;
        o.x = (f16)(sc*(Z.x + Y.x));   // A.re  (row 2qq)
        o.y = (f16)(sc*(Z.y - Y.y));   // A.im
        o.z = (f16)(sc*(Z.y + Y.y));   // B.re  (row 2qq+1)
        o.w = (f16)(sc*(Y.x - Z.x));   // B.im
        *(h4*)&Sp[(size_t)kw*H_ + h0 + 2*qq] = o;
    }
}

// ---------------------------------------------------------------------------
// K2F: fused col-FFT + mag + conv(K=5) + sigmoid + inverse col-FFT.
// f16 LDS transposes (zc h2) -> 25.6 KB total -> 6 blocks/CU.
// grid (P_, 11), block 256.
// ---------------------------------------------------------------------------
__global__ void __launch_bounds__(256) k2f_fused(
        const h2* __restrict__ S, h2* __restrict__ D,
        h2* __restrict__ Sx, const float* __restrict__ fw,
        const float* __restrict__ fb){
    __shared__ h2 zc[16][ZPAD];           // 16.9 KB
    __shared__ f16 mag[16][272];          // 8.7 KB
    __shared__ float cw[5];
    __shared__ float cb;

    const int p = blockIdx.x, tile = blockIdx.y, t = threadIdx.x;
    const int kw0 = tile*12;
    const int nl = min(12, WF - kw0);     // 12 (tiles 0..9) or 9 (tile 10)
    const int NL = nl + 4;                // own + 4 halo lines (<=16)
    const int c = p & (C_-1);
    const h2* Sp = S + (size_t)p*WF*H_;
    if (t < 5)  cw[t] = fw[c*5 + t];
    if (t == 5) cb = fb[c];

    // load NL lines: row ll <-> kwa = kw0+ll-2 (h4 = 2 complex per load)
    for (int idx = t; idx < NL*128; idx += 256){
        int ll = idx >> 7, hh = (idx & 127) << 1;
        int kwa = kw0 + ll - 2;
        int phys = kwa < 0 ? kwa + WF : (kwa > 128 ? kwa - WF : kwa);
        *(h4*)&zc[ll][hh] = *(const h4*)&Sp[(size_t)phys*H_ + hh];
    }
    __syncthreads();

    const int lo = t & 15;
    const int lA = t >> 4;                // row lA holds kw = kw0+lA-2
    const bool act = lA < NL;

    cf aA[16];
    // ---- forward P1: FFT16 over n1 + outer twiddle + transposed write ----
    if (act){
        #pragma unroll
        for (int n1 = 0; n1 < 16; ++n1) aA[n1] = ldz(&zc[lA][lo + 16*n1]);
        fft16r<false>(aA); twchain<false>(aA, lo);
    }
    __syncthreads();
    if (act){
        #pragma unroll
        for (int k0 = 0; k0 < 16; ++k0) stz(&zc[lA][16*lo + (k0 ^ lo)], aA[k0]);
    }
    __syncthreads();
    // ---- forward P2: FFT16 over n0 -> spectrum stays in regs; write mag ----
    if (act){
        #pragma unroll
        for (int n0 = 0; n0 < 16; ++n0) aA[n0] = ldz(&zc[lA][16*n0 + (lo ^ n0)]);
        fft16r<false>(aA);
        #pragma unroll
        for (int k1 = 0; k1 < 16; ++k1)
            mag[lA][lo + 16*k1] = (f16)sqrtf(aA[k1].x*aA[k1].x + aA[k1].y*aA[k1].y);
    }
    __syncthreads();   // mag ready; all zc reads of fwd P2 complete

    // ---- conv(K=5) + sigmoid on regs + inverse P1 on regs ----
    const bool own = act && (lA >= 2) && (lA <= nl + 1);
    if (own){
        const int kw = kw0 + lA - 2;
        int shv[5];
        #pragma unroll
        for (int d = 0; d < 5; ++d){
            int kwa = kw + d - 2;
            shv[d] = (kwa < 0) ? -1 : (kwa > 128 ? 1 : 0);
        }
        #pragma unroll
        for (int k1 = 0; k1 < 16; ++k1){
            int h = lo + 16*k1;
            float acc = cb;
            #pragma unroll
            for (int d = 0; d < 5; ++d){
                int h2i = h + shv[d];
                if (h2i >= 0 && h2i < H_) acc += (float)mag[lA-2+d][h2i] * cw[d];
            }
            float g = 1.f + 1.f/(1.f + __expf(-acc));
            aA[k1] = aA[k1] * g;
        }
        fft16r<true>(aA); twchain<true>(aA, lo);
    }
    __syncthreads();   // order inv-P1 writes after all fwd-P2 zc reads
    if (own){
        #pragma unroll
        for (int n0 = 0; n0 < 16; ++n0)
            stz(&zc[lA][16*lo + (n0 ^ lo)], aA[n0]);
    }
    __syncthreads();
    // ---- inverse P2: FFT16 over k0 -> time domain, store f16 to global ----
    const bool hI = (t >> 4) < nl;
    if (hI){
        const int lI = (t >> 4) + 2;
        #pragma unroll
        for (int k0 = 0; k0 < 16; ++k0) aA[k0] = ldz(&zc[lI][16*k0 + (lo ^ k0)]);
        fft16r<true>(aA);
        int kw = kw0 + (t >> 4);
        h2* dst = (kw < 128) ? (D + ((size_t)p*128 + kw)*H_) : (Sx + (size_t)p*H_);
        #pragma unroll
        for (int n1 = 0; n1 < 16; ++n1){
            h2 o; o.x = (f16)aA[n1].x; o.y = (f16)aA[n1].y;
            dst[lo + 16*n1] = o;
        }
    }
}

// ---------------------------------------------------------------------------
// K5: inverse row transform (Hermitian two-for-one), f16 LDS transposes.
// grid (P_, H_/32), block 256. Reads D/Sx, writes enh (f16, plane-major).
// ---------------------------------------------------------------------------
__global__ void __launch_bounds__(256) k5_irow(const h2* __restrict__ D,
                                               const h2* __restrict__ Sx,
                                               f16* __restrict__ enh){
    __shared__ h2 zc[16][ZPAD];   // 16.9 KB

    const int p = blockIdx.x, tile = blockIdx.y, t = threadIdx.x;
    const int h0 = tile * 32;
    const h2* Dp  = D  + (size_t)p*128*H_;
    const h2* Sxp = Sx + (size_t)p*H_;

    // pack: z[kw] = A + iB, z[256-kw] = conj(A) + i conj(B)
    for (int idx = t; idx < WF*16; idx += 256){
        int kw = idx >> 4, qq = idx & 15;
        const h2* src = (kw < 128) ? (Dp + (size_t)kw*H_) : Sxp;
        h4 ab = *(const h4*)&src[h0 + 2*qq];   // A=(x,y) B=(z,w)
        float Ar = (float)ab.x, Ai = (float)ab.y;
        float Br = (float)ab.z, Bi = (float)ab.w;
        stz(&zc[qq][kw], (cf){Ar - Bi, Ai + Br});
        if (kw > 0 && kw < 128)
            stz(&zc[qq][256-kw], (cf){Ar + Bi, Br - Ai});
    }
    __syncthreads();

    const int q = t >> 4, lo = t & 15;
    cf a[16];
    // P1: IFFT16 over k1 + conj outer twiddle + transposed write
    #pragma unroll
    for (int k1 = 0; k1 < 16; ++k1) a[k1] = ldz(&zc[q][lo + 16*k1]);
    fft16r<true>(a);
    twchain<true>(a, lo);
    __syncthreads();
    #pragma unroll
    for (int n0 = 0; n0 < 16; ++n0) stz(&zc[q][16*lo + (n0 ^ lo)], a[n0]);
    __syncthreads();
    // P2: IFFT16 over k0 -> x[lo + 16n1]
    #pragma unroll
    for (int k0 = 0; k0 < 16; ++k0) a[k0] = ldz(&zc[q][16*k0 + (lo ^ k0)]);
    fft16r<true>(a);
    __syncthreads();
    #pragma unroll
    for (int n1 = 0; n1 < 16; ++n1) stz(&zc[q][lo + 16*n1], a[n1]);  // natural
    __syncthreads();

    const float inv = 1.f / 256.f;
    f16* ep = enh + (size_t)p*H_*W_ + (size_t)h0*W_;
    #pragma unroll
    for (int qq = 0; qq < 16; ++qq){
        cf v = ldz(&zc[qq][t]);
        ep[(2*qq)*W_ + t]   = (f16)(v.x * inv);
        ep[(2*qq+1)*W_ + t] = (f16)(v.y * inv);
    }
}

// ---------------------------------------------------------------------------
// K6: out = x + scale * (mix_w @ enh) via MFMA f16 16x16x32. (unchanged R16)
// grid (B_, 1024), block 256 (4 waves x 16 pix = 64 pix/block).
// ---------------------------------------------------------------------------
__global__ void __launch_bounds__(256) k6_mix(
        const float* __restrict__ x, const float* __restrict__ mixw,
        const float* __restrict__ scale, const f16* __restrict__ enh,
        float* __restrict__ out){
    __shared__ f16 Ml[64][72];         // Ml[o][c], row stride 144B

    const int b = blockIdx.x, pt = blockIdx.y, t = threadIdx.x;
    float* op = out + (size_t)b*C_*H_*W_;
    const float* xp = x + (size_t)b*C_*H_*W_;
    const f16* ep = enh + (size_t)b*C_*H_*W_;

    for (int idx = t; idx < 64*64; idx += 256){
        int o = idx >> 6, c = idx & 63;
        Ml[o][c] = (f16)mixw[idx];
    }
    __syncthreads();

    const int w  = t >> 6;
    const int l  = t & 63;
    const int lj = l & 15;
    const int lk = l >> 4;
    const int pix = pt*64 + w*16 + lj;

    f16x8 af[4][2];
    #pragma unroll
    for (int ot = 0; ot < 4; ++ot){
        #pragma unroll
        for (int kk = 0; kk < 2; ++kk)
            af[ot][kk] = *(const f16x8*)&Ml[ot*16 + lj][kk*32 + lk*8];
    }

    f32x4 acc[4];
    #pragma unroll
    for (int ot = 0; ot < 4; ++ot) acc[ot] = (f32x4){0.f, 0.f, 0.f, 0.f};

    #pragma unroll
    for (int kk = 0; kk < 2; ++kk){
        f16x8 bf;
        #pragma unroll
        for (int j = 0; j < 8; ++j)
            bf[j] = ep[(size_t)(kk*32 + lk*8 + j)*H_*W_ + pix];
        #pragma unroll
        for (int ot = 0; ot < 4; ++ot)
            acc[ot] = __builtin_amdgcn_mfma_f32_16x16x32_f16(af[ot][kk], bf, acc[ot], 0, 0, 0);
    }

    const float sc = scale[0];
    #pragma unroll
    for (int ot = 0; ot < 4; ++ot){
        #pragma unroll
        for (int r = 0; r < 4; ++r){
            int o = ot*16 + lk*4 + r;
            size_t ix = (size_t)o*H_*W_ + pix;
            op[ix] = xp[ix] + sc * acc[ot][r];
        }
    }
}

// ---------------------------------------------------------------------------
extern "C" void kernel_launch(void* const* d_in, const int* in_sizes, int n_in,
                              void* d_out, int out_size, void* d_ws, size_t ws_size,
                              hipStream_t stream){
    const float* x    = (const float*)d_in[0];
    const float* fw   = (const float*)d_in[1];
    const float* fb   = (const float*)d_in[2];
    const float* mixw = (const float*)d_in[3];
    const float* scal = (const float*)d_in[4];
    float* out = (float*)d_out;

    h2* S   = (h2*)d_ws;
    h2* Sx  = (h2*)((char*)d_ws + (size_t)P_*WF*H_*sizeof(h2));
    f16* enh = (f16*)d_ws;        // reuses S region after k2f
    h2* Dmid = (h2*)out;          // D lives in d_out mid-pipeline

    dim3 blk(256);
    k1_row_rfft <<<dim3(P_, H_/32), blk, 0, stream>>>(x, S);
    k2f_fused   <<<dim3(P_, 11),    blk, 0, stream>>>(S, Dmid, Sx, fw, fb);
    k5_irow     <<<dim3(P_, H_/32), blk, 0, stream>>>(Dmid, Sx, enh);
    k6_mix      <<<dim3(B_, 1024),  blk, 0, stream>>>(x, mixw, scal, enh, out);
}

// Round 18
// 225.276 us; speedup vs baseline: 1.0225x; 1.0225x over previous
//
#include <hip/hip_runtime.h>
#include <math.h>

#define B_ 8
#define C_ 64
#define H_ 256
#define W_ 256
#define WF 129
#define P_ (B_*C_)      // 512 planes
#define PI_F 3.14159265358979323846f
#define ZPAD 264        // row stride (4B units) == 8 mod 32 -> 2-way banks

typedef _Float16 f16;
struct h2 { f16 x, y; };          // 4 B
struct h4 { f16 x, y, z, w; };    // 8 B
typedef _Float16 f16x8 __attribute__((ext_vector_type(8)));
typedef float f32x4 __attribute__((ext_vector_type(4)));
typedef float cf __attribute__((ext_vector_type(2)));

__device__ __forceinline__ void stz(h2* p, cf v){ h2 o; o.x=(f16)v.x; o.y=(f16)v.y; *p=o; }
__device__ __forceinline__ cf   ldz(const h2* p){ h2 v=*p; return (cf){(float)v.x,(float)v.y}; }

__device__ __forceinline__ cf cmulv(cf a, cf w){          // a * w
    cf m = a.yy * w.yx;
    cf ms = (cf){-m.x, m.y};
    return a.xx * w + ms;
}
__device__ __forceinline__ cf cmulcv(cf a, cf w){         // a * conj(w)
    cf m = a.yy * w.yx;          // {ay*wy, ay*wx}
    cf wc = (cf){w.x, -w.y};
    return a.xx * wc + m;        // {ax*wx + ay*wy, ay*wx - ax*wy}
}
// forward DFT4 butterfly (W4 = -i rotation)
__device__ __forceinline__ void bf4f(cf u0, cf u1, cf u2, cf u3,
                                     cf& y0, cf& y1, cf& y2, cf& y3){
    cf P = u0 + u2, M = u0 - u2;
    cf Q = u1 + u3, R = u1 - u3;
    cf Rr = (cf){R.y, -R.x};
    y0 = P + Q;  y2 = P - Q;
    y1 = M + Rr; y3 = M - Rr;
}
// inverse DFT4 butterfly (+i rotation)
__device__ __forceinline__ void bf4i(cf u0, cf u1, cf u2, cf u3,
                                     cf& y0, cf& y1, cf& y2, cf& y3){
    cf P = u0 + u2, M = u0 - u2;
    cf Q = u1 + u3, R = u1 - u3;
    cf Ri = (cf){-R.y, R.x};
    y0 = P + Q;  y2 = P - Q;
    y1 = M + Ri; y3 = M - Ri;
}

// full 16-point FFT in registers; radix-4 x 2, constant W16 twiddles.
template<bool INV>
__device__ __forceinline__ void fft16r(cf* a){
    const float C1 = 0.92387953251128674f;
    const float S1 = 0.38268343236508978f;
    const float R2 = 0.70710678118654752f;
    cf b[16];
    #pragma unroll
    for (int m0 = 0; m0 < 4; ++m0){
        cf y0,y1,y2,y3;
        if (!INV) bf4f(a[m0], a[m0+4], a[m0+8], a[m0+12], y0,y1,y2,y3);
        else      bf4i(a[m0], a[m0+4], a[m0+8], a[m0+12], y0,y1,y2,y3);
        b[m0*4+0]=y0; b[m0*4+1]=y1; b[m0*4+2]=y2; b[m0*4+3]=y3;
    }
    const float sg = INV ? 1.f : -1.f;
    b[5]  = cmulv(b[5],  (cf){C1,  sg*S1});
    b[6]  = cmulv(b[6],  (cf){R2,  sg*R2});
    b[7]  = cmulv(b[7],  (cf){S1,  sg*C1});
    b[9]  = cmulv(b[9],  (cf){R2,  sg*R2});
    b[10] = cmulv(b[10], (cf){0.f, sg*1.f});
    b[11] = cmulv(b[11], (cf){-R2, sg*R2});
    b[13] = cmulv(b[13], (cf){S1,  sg*C1});
    b[14] = cmulv(b[14], (cf){-R2, sg*R2});
    b[15] = cmulv(b[15], (cf){-C1, -sg*S1});
    #pragma unroll
    for (int r0 = 0; r0 < 4; ++r0){
        cf y0,y1,y2,y3;
        if (!INV) bf4f(b[r0], b[4+r0], b[8+r0], b[12+r0], y0,y1,y2,y3);
        else      bf4i(b[r0], b[4+r0], b[8+r0], b[12+r0], y0,y1,y2,y3);
        a[r0]    = y0;
        a[r0+4]  = y1;
        a[r0+8]  = y2;
        a[r0+12] = y3;
    }
}

// twiddle table init: twt[lo][k] = W256^{-lo*k} (forward). 256 threads.
#define TW_INIT(twt, t)                                                   \
    {                                                                     \
        int lo_ = (t) >> 4, kk_ = (t) & 15;                               \
        float ang_ = -2.f*PI_F*(float)(lo_*kk_)/256.f;                    \
        twt[lo_][kk_] = (cf){__cosf(ang_), __sinf(ang_)};                 \
    }
// apply: forward multiplies by table, inverse by conj(table)
#define TW_FWD(a, twt, lo)                                                \
    _Pragma("unroll")                                                     \
    for (int k_ = 1; k_ < 16; ++k_) a[k_] = cmulv(a[k_], twt[lo][k_]);
#define TW_INV(a, twt, lo)                                                \
    _Pragma("unroll")                                                     \
    for (int k_ = 1; k_ < 16; ++k_) a[k_] = cmulcv(a[k_], twt[lo][k_]);

// ---------------------------------------------------------------------------
// K1: row rfft (two-for-one), 16x16 register FFT, f16 LDS transposes,
// LDS twiddle table. grid (P_, H_/32), block 256.
// ---------------------------------------------------------------------------
__global__ void __launch_bounds__(256) k1_row_rfft(const float* __restrict__ x,
                                                   h2* __restrict__ S){
    __shared__ h2 zc[16][ZPAD];   // 16.9 KB
    __shared__ cf twt[16][17];    // 2.2 KB

    const int p = blockIdx.x, tile = blockIdx.y, t = threadIdx.x;
    const int h0 = tile * 32;
    const float* xp = x + (size_t)p*H_*W_ + (size_t)h0*W_;

    TW_INIT(twt, t)
    #pragma unroll
    for (int q = 0; q < 16; ++q)
        stz(&zc[q][t], (cf){xp[(2*q)*W_ + t], xp[(2*q+1)*W_ + t]});
    __syncthreads();

    const int q = t >> 4, lo = t & 15;
    cf a[16];
    // P1: FFT16 over n1, outer twiddle (table), transposed write
    #pragma unroll
    for (int n1 = 0; n1 < 16; ++n1) a[n1] = ldz(&zc[q][lo + 16*n1]);
    fft16r<false>(a);
    TW_FWD(a, twt, lo)
    __syncthreads();
    #pragma unroll
    for (int k0 = 0; k0 < 16; ++k0) stz(&zc[q][16*lo + (k0 ^ lo)], a[k0]);
    __syncthreads();
    // P2: FFT16 over n0 -> Z[lo + 16k1]
    #pragma unroll
    for (int n0 = 0; n0 < 16; ++n0) a[n0] = ldz(&zc[q][16*n0 + (lo ^ n0)]);
    fft16r<false>(a);
    __syncthreads();
    #pragma unroll
    for (int k1 = 0; k1 < 16; ++k1) stz(&zc[q][lo + 16*k1], a[k1]);  // natural
    __syncthreads();

    const float sc = 0.5f / 256.f;
    h2* Sp = S + (size_t)p*WF*H_;
    for (int idx = t; idx < WF*16; idx += 256){
        int kw = idx >> 4, qq = idx & 15;
        cf Z = ldz(&zc[qq][kw]);
        cf Y = ldz(&zc[qq][(256-kw)&255]);
        h4 o;
        o.x = (f16)(sc*(Z.x + Y.x));   // A.re  (row 2qq)
        o.y = (f16)(sc*(Z.y - Y.y));   // A.im
        o.z = (f16)(sc*(Z.y + Y.y));   // B.re  (row 2qq+1)
        o.w = (f16)(sc*(Y.x - Z.x));   // B.im
        *(h4*)&Sp[(size_t)kw*H_ + h0 + 2*qq] = o;
    }
}

// ---------------------------------------------------------------------------
// K2F: fused col-FFT + mag + conv(K=5) + sigmoid + inverse col-FFT.
// f16 LDS transposes, LDS twiddle table. grid (P_, 11), block 256.
// ---------------------------------------------------------------------------
__global__ void __launch_bounds__(256) k2f_fused(
        const h2* __restrict__ S, h2* __restrict__ D,
        h2* __restrict__ Sx, const float* __restrict__ fw,
        const float* __restrict__ fb){
    __shared__ h2 zc[16][ZPAD];           // 16.9 KB
    __shared__ f16 mag[16][272];          // 8.7 KB
    __shared__ cf twt[16][17];            // 2.2 KB
    __shared__ float cw[5];
    __shared__ float cb;

    const int p = blockIdx.x, tile = blockIdx.y, t = threadIdx.x;
    const int kw0 = tile*12;
    const int nl = min(12, WF - kw0);     // 12 (tiles 0..9) or 9 (tile 10)
    const int NL = nl + 4;                // own + 4 halo lines (<=16)
    const int c = p & (C_-1);
    const h2* Sp = S + (size_t)p*WF*H_;
    TW_INIT(twt, t)
    if (t < 5)  cw[t] = fw[c*5 + t];
    if (t == 5) cb = fb[c];

    // load NL lines: row ll <-> kwa = kw0+ll-2 (h4 = 2 complex per load)
    for (int idx = t; idx < NL*128; idx += 256){
        int ll = idx >> 7, hh = (idx & 127) << 1;
        int kwa = kw0 + ll - 2;
        int phys = kwa < 0 ? kwa + WF : (kwa > 128 ? kwa - WF : kwa);
        *(h4*)&zc[ll][hh] = *(const h4*)&Sp[(size_t)phys*H_ + hh];
    }
    __syncthreads();

    const int lo = t & 15;
    const int lA = t >> 4;                // row lA holds kw = kw0+lA-2
    const bool act = lA < NL;

    cf aA[16];
    // ---- forward P1: FFT16 over n1 + outer twiddle + transposed write ----
    if (act){
        #pragma unroll
        for (int n1 = 0; n1 < 16; ++n1) aA[n1] = ldz(&zc[lA][lo + 16*n1]);
        fft16r<false>(aA);
        TW_FWD(aA, twt, lo)
    }
    __syncthreads();
    if (act){
        #pragma unroll
        for (int k0 = 0; k0 < 16; ++k0) stz(&zc[lA][16*lo + (k0 ^ lo)], aA[k0]);
    }
    __syncthreads();
    // ---- forward P2: FFT16 over n0 -> spectrum stays in regs; write mag ----
    if (act){
        #pragma unroll
        for (int n0 = 0; n0 < 16; ++n0) aA[n0] = ldz(&zc[lA][16*n0 + (lo ^ n0)]);
        fft16r<false>(aA);
        #pragma unroll
        for (int k1 = 0; k1 < 16; ++k1)
            mag[lA][lo + 16*k1] = (f16)sqrtf(aA[k1].x*aA[k1].x + aA[k1].y*aA[k1].y);
    }
    __syncthreads();   // mag ready; all zc reads of fwd P2 complete

    // ---- conv(K=5) + sigmoid on regs + inverse P1 on regs ----
    const bool own = act && (lA >= 2) && (lA <= nl + 1);
    if (own){
        const int kw = kw0 + lA - 2;
        int shv[5];
        #pragma unroll
        for (int d = 0; d < 5; ++d){
            int kwa = kw + d - 2;
            shv[d] = (kwa < 0) ? -1 : (kwa > 128 ? 1 : 0);
        }
        #pragma unroll
        for (int k1 = 0; k1 < 16; ++k1){
            int h = lo + 16*k1;
            float acc = cb;
            #pragma unroll
            for (int d = 0; d < 5; ++d){
                int h2i = h + shv[d];
                if (h2i >= 0 && h2i < H_) acc += (float)mag[lA-2+d][h2i] * cw[d];
            }
            float g = 1.f + 1.f/(1.f + __expf(-acc));
            aA[k1] = aA[k1] * g;
        }
        fft16r<true>(aA);
        TW_INV(aA, twt, lo)
    }
    __syncthreads();   // order inv-P1 writes after all fwd-P2 zc reads
    if (own){
        #pragma unroll
        for (int n0 = 0; n0 < 16; ++n0)
            stz(&zc[lA][16*lo + (n0 ^ lo)], aA[n0]);
    }
    __syncthreads();
    // ---- inverse P2: FFT16 over k0 -> time domain, store f16 to global ----
    const bool hI = (t >> 4) < nl;
    if (hI){
        const int lI = (t >> 4) + 2;
        #pragma unroll
        for (int k0 = 0; k0 < 16; ++k0) aA[k0] = ldz(&zc[lI][16*k0 + (lo ^ k0)]);
        fft16r<true>(aA);
        int kw = kw0 + (t >> 4);
        h2* dst = (kw < 128) ? (D + ((size_t)p*128 + kw)*H_) : (Sx + (size_t)p*H_);
        #pragma unroll
        for (int n1 = 0; n1 < 16; ++n1){
            h2 o; o.x = (f16)aA[n1].x; o.y = (f16)aA[n1].y;
            dst[lo + 16*n1] = o;
        }
    }
}

// ---------------------------------------------------------------------------
// K5: inverse row transform (Hermitian two-for-one), f16 LDS transposes,
// LDS twiddle table. grid (P_, H_/32), block 256.
// ---------------------------------------------------------------------------
__global__ void __launch_bounds__(256) k5_irow(const h2* __restrict__ D,
                                               const h2* __restrict__ Sx,
                                               f16* __restrict__ enh){
    __shared__ h2 zc[16][ZPAD];   // 16.9 KB
    __shared__ cf twt[16][17];    // 2.2 KB

    const int p = blockIdx.x, tile = blockIdx.y, t = threadIdx.x;
    const int h0 = tile * 32;
    const h2* Dp  = D  + (size_t)p*128*H_;
    const h2* Sxp = Sx + (size_t)p*H_;

    TW_INIT(twt, t)
    // pack: z[kw] = A + iB, z[256-kw] = conj(A) + i conj(B)
    for (int idx = t; idx < WF*16; idx += 256){
        int kw = idx >> 4, qq = idx & 15;
        const h2* src = (kw < 128) ? (Dp + (size_t)kw*H_) : Sxp;
        h4 ab = *(const h4*)&src[h0 + 2*qq];   // A=(x,y) B=(z,w)
        float Ar = (float)ab.x, Ai = (float)ab.y;
        float Br = (float)ab.z, Bi = (float)ab.w;
        stz(&zc[qq][kw], (cf){Ar - Bi, Ai + Br});
        if (kw > 0 && kw < 128)
            stz(&zc[qq][256-kw], (cf){Ar + Bi, Br - Ai});
    }
    __syncthreads();

    const int q = t >> 4, lo = t & 15;
    cf a[16];
    // P1: IFFT16 over k1 + conj outer twiddle (table) + transposed write
    #pragma unroll
    for (int k1 = 0; k1 < 16; ++k1) a[k1] = ldz(&zc[q][lo + 16*k1]);
    fft16r<true>(a);
    TW_INV(a, twt, lo)
    __syncthreads();
    #pragma unroll
    for (int n0 = 0; n0 < 16; ++n0) stz(&zc[q][16*lo + (n0 ^ lo)], a[n0]);
    __syncthreads();
    // P2: IFFT16 over k0 -> x[lo + 16n1]
    #pragma unroll
    for (int k0 = 0; k0 < 16; ++k0) a[k0] = ldz(&zc[q][16*k0 + (lo ^ k0)]);
    fft16r<true>(a);
    __syncthreads();
    #pragma unroll
    for (int n1 = 0; n1 < 16; ++n1) stz(&zc[q][lo + 16*n1], a[n1]);  // natural
    __syncthreads();

    const float inv = 1.f / 256.f;
    f16* ep = enh + (size_t)p*H_*W_ + (size_t)h0*W_;
    #pragma unroll
    for (int qq = 0; qq < 16; ++qq){
        cf v = ldz(&zc[qq][t]);
        ep[(2*qq)*W_ + t]   = (f16)(v.x * inv);
        ep[(2*qq+1)*W_ + t] = (f16)(v.y * inv);
    }
}

// ---------------------------------------------------------------------------
// K6: out = x + scale * (mix_w @ enh) via MFMA f16 16x16x32. (unchanged R17)
// grid (B_, 1024), block 256 (4 waves x 16 pix = 64 pix/block).
// ---------------------------------------------------------------------------
__global__ void __launch_bounds__(256) k6_mix(
        const float* __restrict__ x, const float* __restrict__ mixw,
        const float* __restrict__ scale, const f16* __restrict__ enh,
        float* __restrict__ out){
    __shared__ f16 Ml[64][72];         // Ml[o][c], row stride 144B

    const int b = blockIdx.x, pt = blockIdx.y, t = threadIdx.x;
    float* op = out + (size_t)b*C_*H_*W_;
    const float* xp = x + (size_t)b*C_*H_*W_;
    const f16* ep = enh + (size_t)b*C_*H_*W_;

    for (int idx = t; idx < 64*64; idx += 256){
        int o = idx >> 6, c = idx & 63;
        Ml[o][c] = (f16)mixw[idx];
    }
    __syncthreads();

    const int w  = t >> 6;
    const int l  = t & 63;
    const int lj = l & 15;
    const int lk = l >> 4;
    const int pix = pt*64 + w*16 + lj;

    f16x8 af[4][2];
    #pragma unroll
    for (int ot = 0; ot < 4; ++ot){
        #pragma unroll
        for (int kk = 0; kk < 2; ++kk)
            af[ot][kk] = *(const f16x8*)&Ml[ot*16 + lj][kk*32 + lk*8];
    }

    f32x4 acc[4];
    #pragma unroll
    for (int ot = 0; ot < 4; ++ot) acc[ot] = (f32x4){0.f, 0.f, 0.f, 0.f};

    #pragma unroll
    for (int kk = 0; kk < 2; ++kk){
        f16x8 bf;
        #pragma unroll
        for (int j = 0; j < 8; ++j)
            bf[j] = ep[(size_t)(kk*32 + lk*8 + j)*H_*W_ + pix];
        #pragma unroll
        for (int ot = 0; ot < 4; ++ot)
            acc[ot] = __builtin_amdgcn_mfma_f32_16x16x32_f16(af[ot][kk], bf, acc[ot], 0, 0, 0);
    }

    const float sc = scale[0];
    #pragma unroll
    for (int ot = 0; ot < 4; ++ot){
        #pragma unroll
        for (int r = 0; r < 4; ++r){
            int o = ot*16 + lk*4 + r;
            size_t ix = (size_t)o*H_*W_ + pix;
            op[ix] = xp[ix] + sc * acc[ot][r];
        }
    }
}

// ---------------------------------------------------------------------------
extern "C" void kernel_launch(void* const* d_in, const int* in_sizes, int n_in,
                              void* d_out, int out_size, void* d_ws, size_t ws_size,
                              hipStream_t stream){
    const float* x    = (const float*)d_in[0];
    const float* fw   = (const float*)d_in[1];
    const float* fb   = (const float*)d_in[2];
    const float* mixw = (const float*)d_in[3];
    const float* scal = (const float*)d_in[4];
    float* out = (float*)d_out;

    h2* S   = (h2*)d_ws;
    h2* Sx  = (h2*)((char*)d_ws + (size_t)P_*WF*H_*sizeof(h2));
    f16* enh = (f16*)d_ws;        // reuses S region after k2f
    h2* Dmid = (h2*)out;          // D lives in d_out mid-pipeline

    dim3 blk(256);
    k1_row_rfft <<<dim3(P_, H_/32), blk, 0, stream>>>(x, S);
    k2f_fused   <<<dim3(P_, 11),    blk, 0, stream>>>(S, Dmid, Sx, fw, fb);
    k5_irow     <<<dim3(P_, H_/32), blk, 0, stream>>>(Dmid, Sx, enh);
    k6_mix      <<<dim3(B_, 1024),  blk, 0, stream>>>(x, mixw, scal, enh, out);
}

// Round 19
// 218.866 us; speedup vs baseline: 1.0525x; 1.0293x over previous
//
#include <hip/hip_runtime.h>
#include <math.h>

#define B_ 8
#define C_ 64
#define H_ 256
#define W_ 256
#define WF 129
#define P_ (B_*C_)      // 512 planes
#define PI_F 3.14159265358979323846f
#define ZPAD 264        // row stride (4B units) == 8 mod 32 -> 2-way banks

typedef _Float16 f16;
struct h2 { f16 x, y; };          // 4 B
struct h4 { f16 x, y, z, w; };    // 8 B
typedef _Float16 f16x8 __attribute__((ext_vector_type(8)));
typedef float f32x4 __attribute__((ext_vector_type(4)));
typedef float cf __attribute__((ext_vector_type(2)));

__device__ __forceinline__ void stz(h2* p, cf v){ h2 o; o.x=(f16)v.x; o.y=(f16)v.y; *p=o; }
__device__ __forceinline__ cf   ldz(const h2* p){ h2 v=*p; return (cf){(float)v.x,(float)v.y}; }

// ---- hand-emitted VOP3P packed-f32 complex primitives -----------------------
// op_sel[i]: which half of src i feeds the LOW lane; op_sel_hi[i]: HIGH lane.
// neg_lo/neg_hi negate src i's operand in that lane.
__device__ __forceinline__ cf padd(cf a, cf b){
    cf d; asm("v_pk_add_f32 %0, %1, %2" : "=v"(d) : "v"(a), "v"(b)); return d;
}
__device__ __forceinline__ cf psub(cf a, cf b){
    cf d; asm("v_pk_add_f32 %0, %1, %2 neg_lo:[0,1] neg_hi:[0,1]"
              : "=v"(d) : "v"(a), "v"(b)); return d;
}
// M + (-i)R = {M.x + R.y, M.y - R.x}
__device__ __forceinline__ cf paddmi(cf M, cf R){
    cf d; asm("v_pk_add_f32 %0, %1, %2 op_sel:[0,1] op_sel_hi:[1,0] neg_hi:[0,1]"
              : "=v"(d) : "v"(M), "v"(R)); return d;
}
// M + (+i)R = {M.x - R.y, M.y + R.x}
__device__ __forceinline__ cf paddpi(cf M, cf R){
    cf d; asm("v_pk_add_f32 %0, %1, %2 op_sel:[0,1] op_sel_hi:[1,0] neg_lo:[0,1]"
              : "=v"(d) : "v"(M), "v"(R)); return d;
}
// a * w : t = {a.x*w.x, a.x*w.y}; d = {-w.y*a.y + t.x, w.x*a.y + t.y}
__device__ __forceinline__ cf cmulv(cf a, cf w){
    cf t, d;
    asm("v_pk_mul_f32 %0, %1, %2 op_sel_hi:[0,1]" : "=v"(t) : "v"(a), "v"(w));
    asm("v_pk_fma_f32 %0, %1, %2, %3 op_sel:[1,1,0] op_sel_hi:[1,0,1] neg_lo:[0,1,0]"
        : "=v"(d) : "v"(a), "v"(w), "v"(t));
    return d;
}
// a * conj(w): t = {a.x*w.x, a.y*w.x}; d = {a.y*w.y + t.x, -a.x*w.y + t.y}
__device__ __forceinline__ cf cmulcv(cf a, cf w){
    cf t, d;
    asm("v_pk_mul_f32 %0, %1, %2 op_sel_hi:[1,0]" : "=v"(t) : "v"(a), "v"(w));
    asm("v_pk_fma_f32 %0, %1, %2, %3 op_sel:[1,1,0] op_sel_hi:[0,1,1] neg_hi:[1,0,0]"
        : "=v"(d) : "v"(a), "v"(w), "v"(t));
    return d;
}

// full 16-point FFT in registers; radix-4 x 2, constant W16 twiddles.
// All complex arithmetic in packed VOP3P (82 pk instrs).
template<bool INV>
__device__ __forceinline__ void fft16r(cf* a){
    const float C1 = 0.92387953251128674f;
    const float S1 = 0.38268343236508978f;
    const float R2 = 0.70710678118654752f;
    cf b[16];
    #pragma unroll
    for (int m0 = 0; m0 < 4; ++m0){
        cf u0 = a[m0], u1 = a[m0+4], u2 = a[m0+8], u3 = a[m0+12];
        cf P = padd(u0,u2), M = psub(u0,u2);
        cf Q = padd(u1,u3), R = psub(u1,u3);
        b[m0*4+0] = padd(P,Q);
        b[m0*4+2] = psub(P,Q);
        if (!INV){ b[m0*4+1] = paddmi(M,R); b[m0*4+3] = paddpi(M,R); }
        else     { b[m0*4+1] = paddpi(M,R); b[m0*4+3] = paddmi(M,R); }
    }
    const float sg = INV ? 1.f : -1.f;
    b[5]  = cmulv(b[5],  (cf){C1,  sg*S1});
    b[6]  = cmulv(b[6],  (cf){R2,  sg*R2});
    b[7]  = cmulv(b[7],  (cf){S1,  sg*C1});
    b[9]  = cmulv(b[9],  (cf){R2,  sg*R2});
    b[10] = cmulv(b[10], (cf){0.f, sg*1.f});
    b[11] = cmulv(b[11], (cf){-R2, sg*R2});
    b[13] = cmulv(b[13], (cf){S1,  sg*C1});
    b[14] = cmulv(b[14], (cf){-R2, sg*R2});
    b[15] = cmulv(b[15], (cf){-C1, -sg*S1});
    #pragma unroll
    for (int r0 = 0; r0 < 4; ++r0){
        cf u0 = b[r0], u1 = b[4+r0], u2 = b[8+r0], u3 = b[12+r0];
        cf P = padd(u0,u2), M = psub(u0,u2);
        cf Q = padd(u1,u3), R = psub(u1,u3);
        a[r0]    = padd(P,Q);
        a[r0+8]  = psub(P,Q);
        if (!INV){ a[r0+4] = paddmi(M,R); a[r0+12] = paddpi(M,R); }
        else     { a[r0+4] = paddpi(M,R); a[r0+12] = paddmi(M,R); }
    }
}

// twiddle table init: twt[lo][k] = W256^{-lo*k} (forward). 256 threads.
#define TW_INIT(twt, t)                                                   \
    {                                                                     \
        int lo_ = (t) >> 4, kk_ = (t) & 15;                               \
        float ang_ = -2.f*PI_F*(float)(lo_*kk_)/256.f;                    \
        twt[lo_][kk_] = (cf){__cosf(ang_), __sinf(ang_)};                 \
    }
#define TW_FWD(a, twt, lo)                                                \
    _Pragma("unroll")                                                     \
    for (int k_ = 1; k_ < 16; ++k_) a[k_] = cmulv(a[k_], twt[lo][k_]);
#define TW_INV(a, twt, lo)                                                \
    _Pragma("unroll")                                                     \
    for (int k_ = 1; k_ < 16; ++k_) a[k_] = cmulcv(a[k_], twt[lo][k_]);

// ---------------------------------------------------------------------------
// K1: row rfft (two-for-one), 16x16 register FFT, f16 LDS transposes,
// LDS twiddle table. grid (P_, H_/32), block 256.
// ---------------------------------------------------------------------------
__global__ void __launch_bounds__(256) k1_row_rfft(const float* __restrict__ x,
                                                   h2* __restrict__ S){
    __shared__ h2 zc[16][ZPAD];   // 16.9 KB
    __shared__ cf twt[16][17];    // 2.2 KB

    const int p = blockIdx.x, tile = blockIdx.y, t = threadIdx.x;
    const int h0 = tile * 32;
    const float* xp = x + (size_t)p*H_*W_ + (size_t)h0*W_;

    TW_INIT(twt, t)
    #pragma unroll
    for (int q = 0; q < 16; ++q)
        stz(&zc[q][t], (cf){xp[(2*q)*W_ + t], xp[(2*q+1)*W_ + t]});
    __syncthreads();

    const int q = t >> 4, lo = t & 15;
    cf a[16];
    // P1: FFT16 over n1, outer twiddle (table), transposed write
    #pragma unroll
    for (int n1 = 0; n1 < 16; ++n1) a[n1] = ldz(&zc[q][lo + 16*n1]);
    fft16r<false>(a);
    TW_FWD(a, twt, lo)
    __syncthreads();
    #pragma unroll
    for (int k0 = 0; k0 < 16; ++k0) stz(&zc[q][16*lo + (k0 ^ lo)], a[k0]);
    __syncthreads();
    // P2: FFT16 over n0 -> Z[lo + 16k1]
    #pragma unroll
    for (int n0 = 0; n0 < 16; ++n0) a[n0] = ldz(&zc[q][16*n0 + (lo ^ n0)]);
    fft16r<false>(a);
    __syncthreads();
    #pragma unroll
    for (int k1 = 0; k1 < 16; ++k1) stz(&zc[q][lo + 16*k1], a[k1]);  // natural
    __syncthreads();

    const float sc = 0.5f / 256.f;
    h2* Sp = S + (size_t)p*WF*H_;
    for (int idx = t; idx < WF*16; idx += 256){
        int kw = idx >> 4, qq = idx & 15;
        cf Z = ldz(&zc[qq][kw]);
        cf Y = ldz(&zc[qq][(256-kw)&255]);
        h4 o;
        o.x = (f16)(sc*(Z.x + Y.x));   // A.re  (row 2qq)
        o.y = (f16)(sc*(Z.y - Y.y));   // A.im
        o.z = (f16)(sc*(Z.y + Y.y));   // B.re  (row 2qq+1)
        o.w = (f16)(sc*(Y.x - Z.x));   // B.im
        *(h4*)&Sp[(size_t)kw*H_ + h0 + 2*qq] = o;
    }
}

// ---------------------------------------------------------------------------
// K2F: fused col-FFT + mag + conv(K=5) + sigmoid + inverse col-FFT.
// f16 LDS transposes, LDS twiddle table, VOP3P FFT math.
// grid (P_, 11), block 256.
// ---------------------------------------------------------------------------
__global__ void __launch_bounds__(256) k2f_fused(
        const h2* __restrict__ S, h2* __restrict__ D,
        h2* __restrict__ Sx, const float* __restrict__ fw,
        const float* __restrict__ fb){
    __shared__ h2 zc[16][ZPAD];           // 16.9 KB
    __shared__ f16 mag[16][272];          // 8.7 KB
    __shared__ cf twt[16][17];            // 2.2 KB
    __shared__ float cw[5];
    __shared__ float cb;

    const int p = blockIdx.x, tile = blockIdx.y, t = threadIdx.x;
    const int kw0 = tile*12;
    const int nl = min(12, WF - kw0);     // 12 (tiles 0..9) or 9 (tile 10)
    const int NL = nl + 4;                // own + 4 halo lines (<=16)
    const int c = p & (C_-1);
    const h2* Sp = S + (size_t)p*WF*H_;
    TW_INIT(twt, t)
    if (t < 5)  cw[t] = fw[c*5 + t];
    if (t == 5) cb = fb[c];

    // load NL lines: row ll <-> kwa = kw0+ll-2 (h4 = 2 complex per load)
    for (int idx = t; idx < NL*128; idx += 256){
        int ll = idx >> 7, hh = (idx & 127) << 1;
        int kwa = kw0 + ll - 2;
        int phys = kwa < 0 ? kwa + WF : (kwa > 128 ? kwa - WF : kwa);
        *(h4*)&zc[ll][hh] = *(const h4*)&Sp[(size_t)phys*H_ + hh];
    }
    __syncthreads();

    const int lo = t & 15;
    const int lA = t >> 4;                // row lA holds kw = kw0+lA-2
    const bool act = lA < NL;

    cf aA[16];
    // ---- forward P1: FFT16 over n1 + outer twiddle + transposed write ----
    if (act){
        #pragma unroll
        for (int n1 = 0; n1 < 16; ++n1) aA[n1] = ldz(&zc[lA][lo + 16*n1]);
        fft16r<false>(aA);
        TW_FWD(aA, twt, lo)
    }
    __syncthreads();
    if (act){
        #pragma unroll
        for (int k0 = 0; k0 < 16; ++k0) stz(&zc[lA][16*lo + (k0 ^ lo)], aA[k0]);
    }
    __syncthreads();
    // ---- forward P2: FFT16 over n0 -> spectrum stays in regs; write mag ----
    if (act){
        #pragma unroll
        for (int n0 = 0; n0 < 16; ++n0) aA[n0] = ldz(&zc[lA][16*n0 + (lo ^ n0)]);
        fft16r<false>(aA);
        #pragma unroll
        for (int k1 = 0; k1 < 16; ++k1)
            mag[lA][lo + 16*k1] = (f16)sqrtf(aA[k1].x*aA[k1].x + aA[k1].y*aA[k1].y);
    }
    __syncthreads();   // mag ready; all zc reads of fwd P2 complete

    // ---- conv(K=5) + sigmoid on regs + inverse P1 on regs ----
    const bool own = act && (lA >= 2) && (lA <= nl + 1);
    if (own){
        const int kw = kw0 + lA - 2;
        int shv[5];
        #pragma unroll
        for (int d = 0; d < 5; ++d){
            int kwa = kw + d - 2;
            shv[d] = (kwa < 0) ? -1 : (kwa > 128 ? 1 : 0);
        }
        #pragma unroll
        for (int k1 = 0; k1 < 16; ++k1){
            int h = lo + 16*k1;
            float acc = cb;
            #pragma unroll
            for (int d = 0; d < 5; ++d){
                int h2i = h + shv[d];
                if (h2i >= 0 && h2i < H_) acc += (float)mag[lA-2+d][h2i] * cw[d];
            }
            float g = 1.f + 1.f/(1.f + __expf(-acc));
            aA[k1] = aA[k1] * g;
        }
        fft16r<true>(aA);
        TW_INV(aA, twt, lo)
    }
    __syncthreads();   // order inv-P1 writes after all fwd-P2 zc reads
    if (own){
        #pragma unroll
        for (int n0 = 0; n0 < 16; ++n0)
            stz(&zc[lA][16*lo + (n0 ^ lo)], aA[n0]);
    }
    __syncthreads();
    // ---- inverse P2: FFT16 over k0 -> time domain, store f16 to global ----
    const bool hI = (t >> 4) < nl;
    if (hI){
        const int lI = (t >> 4) + 2;
        #pragma unroll
        for (int k0 = 0; k0 < 16; ++k0) aA[k0] = ldz(&zc[lI][16*k0 + (lo ^ k0)]);
        fft16r<true>(aA);
        int kw = kw0 + (t >> 4);
        h2* dst = (kw < 128) ? (D + ((size_t)p*128 + kw)*H_) : (Sx + (size_t)p*H_);
        #pragma unroll
        for (int n1 = 0; n1 < 16; ++n1){
            h2 o; o.x = (f16)aA[n1].x; o.y = (f16)aA[n1].y;
            dst[lo + 16*n1] = o;
        }
    }
}

// ---------------------------------------------------------------------------
// K5: inverse row transform (Hermitian two-for-one), f16 LDS transposes,
// LDS twiddle table, VOP3P FFT math. grid (P_, H_/32), block 256.
// ---------------------------------------------------------------------------
__global__ void __launch_bounds__(256) k5_irow(const h2* __restrict__ D,
                                               const h2* __restrict__ Sx,
                                               f16* __restrict__ enh){
    __shared__ h2 zc[16][ZPAD];   // 16.9 KB
    __shared__ cf twt[16][17];    // 2.2 KB

    const int p = blockIdx.x, tile = blockIdx.y, t = threadIdx.x;
    const int h0 = tile * 32;
    const h2* Dp  = D  + (size_t)p*128*H_;
    const h2* Sxp = Sx + (size_t)p*H_;

    TW_INIT(twt, t)
    // pack: z[kw] = A + iB, z[256-kw] = conj(A) + i conj(B)
    for (int idx = t; idx < WF*16; idx += 256){
        int kw = idx >> 4, qq = idx & 15;
        const h2* src = (kw < 128) ? (Dp + (size_t)kw*H_) : Sxp;
        h4 ab = *(const h4*)&src[h0 + 2*qq];   // A=(x,y) B=(z,w)
        float Ar = (float)ab.x, Ai = (float)ab.y;
        float Br = (float)ab.z, Bi = (float)ab.w;
        stz(&zc[qq][kw], (cf){Ar - Bi, Ai + Br});
        if (kw > 0 && kw < 128)
            stz(&zc[qq][256-kw], (cf){Ar + Bi, Br - Ai});
    }
    __syncthreads();

    const int q = t >> 4, lo = t & 15;
    cf a[16];
    // P1: IFFT16 over k1 + conj outer twiddle (table) + transposed write
    #pragma unroll
    for (int k1 = 0; k1 < 16; ++k1) a[k1] = ldz(&zc[q][lo + 16*k1]);
    fft16r<true>(a);
    TW_INV(a, twt, lo)
    __syncthreads();
    #pragma unroll
    for (int n0 = 0; n0 < 16; ++n0) stz(&zc[q][16*lo + (n0 ^ lo)], a[n0]);
    __syncthreads();
    // P2: IFFT16 over k0 -> x[lo + 16n1]
    #pragma unroll
    for (int k0 = 0; k0 < 16; ++k0) a[k0] = ldz(&zc[q][16*k0 + (lo ^ k0)]);
    fft16r<true>(a);
    __syncthreads();
    #pragma unroll
    for (int n1 = 0; n1 < 16; ++n1) stz(&zc[q][lo + 16*n1], a[n1]);  // natural
    __syncthreads();

    const float inv = 1.f / 256.f;
    f16* ep = enh + (size_t)p*H_*W_ + (size_t)h0*W_;
    #pragma unroll
    for (int qq = 0; qq < 16; ++qq){
        cf v = ldz(&zc[qq][t]);
        ep[(2*qq)*W_ + t]   = (f16)(v.x * inv);
        ep[(2*qq+1)*W_ + t] = (f16)(v.y * inv);
    }
}

// ---------------------------------------------------------------------------
// K6: out = x + scale * (mix_w @ enh) via MFMA f16 16x16x32. (unchanged R18)
// grid (B_, 1024), block 256 (4 waves x 16 pix = 64 pix/block).
// ---------------------------------------------------------------------------
__global__ void __launch_bounds__(256) k6_mix(
        const float* __restrict__ x, const float* __restrict__ mixw,
        const float* __restrict__ scale, const f16* __restrict__ enh,
        float* __restrict__ out){
    __shared__ f16 Ml[64][72];         // Ml[o][c], row stride 144B

    const int b = blockIdx.x, pt = blockIdx.y, t = threadIdx.x;
    float* op = out + (size_t)b*C_*H_*W_;
    const float* xp = x + (size_t)b*C_*H_*W_;
    const f16* ep = enh + (size_t)b*C_*H_*W_;

    for (int idx = t; idx < 64*64; idx += 256){
        int o = idx >> 6, c = idx & 63;
        Ml[o][c] = (f16)mixw[idx];
    }
    __syncthreads();

    const int w  = t >> 6;
    const int l  = t & 63;
    const int lj = l & 15;
    const int lk = l >> 4;
    const int pix = pt*64 + w*16 + lj;

    f16x8 af[4][2];
    #pragma unroll
    for (int ot = 0; ot < 4; ++ot){
        #pragma unroll
        for (int kk = 0; kk < 2; ++kk)
            af[ot][kk] = *(const f16x8*)&Ml[ot*16 + lj][kk*32 + lk*8];
    }

    f32x4 acc[4];
    #pragma unroll
    for (int ot = 0; ot < 4; ++ot) acc[ot] = (f32x4){0.f, 0.f, 0.f, 0.f};

    #pragma unroll
    for (int kk = 0; kk < 2; ++kk){
        f16x8 bf;
        #pragma unroll
        for (int j = 0; j < 8; ++j)
            bf[j] = ep[(size_t)(kk*32 + lk*8 + j)*H_*W_ + pix];
        #pragma unroll
        for (int ot = 0; ot < 4; ++ot)
            acc[ot] = __builtin_amdgcn_mfma_f32_16x16x32_f16(af[ot][kk], bf, acc[ot], 0, 0, 0);
    }

    const float sc = scale[0];
    #pragma unroll
    for (int ot = 0; ot < 4; ++ot){
        #pragma unroll
        for (int r = 0; r < 4; ++r){
            int o = ot*16 + lk*4 + r;
            size_t ix = (size_t)o*H_*W_ + pix;
            op[ix] = xp[ix] + sc * acc[ot][r];
        }
    }
}

// ---------------------------------------------------------------------------
extern "C" void kernel_launch(void* const* d_in, const int* in_sizes, int n_in,
                              void* d_out, int out_size, void* d_ws, size_t ws_size,
                              hipStream_t stream){
    const float* x    = (const float*)d_in[0];
    const float* fw   = (const float*)d_in[1];
    const float* fb   = (const float*)d_in[2];
    const float* mixw = (const float*)d_in[3];
    const float* scal = (const float*)d_in[4];
    float* out = (float*)d_out;

    h2* S   = (h2*)d_ws;
    h2* Sx  = (h2*)((char*)d_ws + (size_t)P_*WF*H_*sizeof(h2));
    f16* enh = (f16*)d_ws;        // reuses S region after k2f
    h2* Dmid = (h2*)out;          // D lives in d_out mid-pipeline

    dim3 blk(256);
    k1_row_rfft <<<dim3(P_, H_/32), blk, 0, stream>>>(x, S);
    k2f_fused   <<<dim3(P_, 11),    blk, 0, stream>>>(S, Dmid, Sx, fw, fb);
    k5_irow     <<<dim3(P_, H_/32), blk, 0, stream>>>(Dmid, Sx, enh);
    k6_mix      <<<dim3(B_, 1024),  blk, 0, stream>>>(x, mixw, scal, enh, out);
}

// Round 20
// 214.348 us; speedup vs baseline: 1.0747x; 1.0211x over previous
//
#include <hip/hip_runtime.h>
#include <math.h>

#define B_ 8
#define C_ 64
#define H_ 256
#define W_ 256
#define WF 129
#define P_ (B_*C_)      // 512 planes
#define PI_F 3.14159265358979323846f
#define ZPAD 264        // row stride (4B units) == 8 mod 32 -> 2-way banks

typedef _Float16 f16;
struct h2 { f16 x, y; };          // 4 B
struct h4 { f16 x, y, z, w; };    // 8 B
typedef _Float16 f16x8 __attribute__((ext_vector_type(8)));
typedef float f32x4 __attribute__((ext_vector_type(4)));
typedef float cf __attribute__((ext_vector_type(2)));

__device__ __forceinline__ void stz(h2* p, cf v){ h2 o; o.x=(f16)v.x; o.y=(f16)v.y; *p=o; }
__device__ __forceinline__ cf   ldz(const h2* p){ h2 v=*p; return (cf){(float)v.x,(float)v.y}; }

// ---- hand-emitted VOP3P packed-f32 complex primitives -----------------------
__device__ __forceinline__ cf padd(cf a, cf b){
    cf d; asm("v_pk_add_f32 %0, %1, %2" : "=v"(d) : "v"(a), "v"(b)); return d;
}
__device__ __forceinline__ cf psub(cf a, cf b){
    cf d; asm("v_pk_add_f32 %0, %1, %2 neg_lo:[0,1] neg_hi:[0,1]"
              : "=v"(d) : "v"(a), "v"(b)); return d;
}
// M + (-i)R = {M.x + R.y, M.y - R.x}
__device__ __forceinline__ cf paddmi(cf M, cf R){
    cf d; asm("v_pk_add_f32 %0, %1, %2 op_sel:[0,1] op_sel_hi:[1,0] neg_hi:[0,1]"
              : "=v"(d) : "v"(M), "v"(R)); return d;
}
// M + (+i)R = {M.x - R.y, M.y + R.x}
__device__ __forceinline__ cf paddpi(cf M, cf R){
    cf d; asm("v_pk_add_f32 %0, %1, %2 op_sel:[0,1] op_sel_hi:[1,0] neg_lo:[0,1]"
              : "=v"(d) : "v"(M), "v"(R)); return d;
}
// a * w : t = {a.x*w.x, a.x*w.y}; d = {-w.y*a.y + t.x, w.x*a.y + t.y}
__device__ __forceinline__ cf cmulv(cf a, cf w){
    cf t, d;
    asm("v_pk_mul_f32 %0, %1, %2 op_sel_hi:[0,1]" : "=v"(t) : "v"(a), "v"(w));
    asm("v_pk_fma_f32 %0, %1, %2, %3 op_sel:[1,1,0] op_sel_hi:[1,0,1] neg_lo:[0,1,0]"
        : "=v"(d) : "v"(a), "v"(w), "v"(t));
    return d;
}
// a * conj(w): t = {a.x*w.x, a.y*w.x}; d = {a.y*w.y + t.x, -a.x*w.y + t.y}
__device__ __forceinline__ cf cmulcv(cf a, cf w){
    cf t, d;
    asm("v_pk_mul_f32 %0, %1, %2 op_sel_hi:[1,0]" : "=v"(t) : "v"(a), "v"(w));
    asm("v_pk_fma_f32 %0, %1, %2, %3 op_sel:[1,1,0] op_sel_hi:[0,1,1] neg_hi:[1,0,0]"
        : "=v"(d) : "v"(a), "v"(w), "v"(t));
    return d;
}

// full 16-point FFT in registers; radix-4 x 2, constant W16 twiddles.
template<bool INV>
__device__ __forceinline__ void fft16r(cf* a){
    const float C1 = 0.92387953251128674f;
    const float S1 = 0.38268343236508978f;
    const float R2 = 0.70710678118654752f;
    cf b[16];
    #pragma unroll
    for (int m0 = 0; m0 < 4; ++m0){
        cf u0 = a[m0], u1 = a[m0+4], u2 = a[m0+8], u3 = a[m0+12];
        cf P = padd(u0,u2), M = psub(u0,u2);
        cf Q = padd(u1,u3), R = psub(u1,u3);
        b[m0*4+0] = padd(P,Q);
        b[m0*4+2] = psub(P,Q);
        if (!INV){ b[m0*4+1] = paddmi(M,R); b[m0*4+3] = paddpi(M,R); }
        else     { b[m0*4+1] = paddpi(M,R); b[m0*4+3] = paddmi(M,R); }
    }
    const float sg = INV ? 1.f : -1.f;
    b[5]  = cmulv(b[5],  (cf){C1,  sg*S1});
    b[6]  = cmulv(b[6],  (cf){R2,  sg*R2});
    b[7]  = cmulv(b[7],  (cf){S1,  sg*C1});
    b[9]  = cmulv(b[9],  (cf){R2,  sg*R2});
    b[10] = cmulv(b[10], (cf){0.f, sg*1.f});
    b[11] = cmulv(b[11], (cf){-R2, sg*R2});
    b[13] = cmulv(b[13], (cf){S1,  sg*C1});
    b[14] = cmulv(b[14], (cf){-R2, sg*R2});
    b[15] = cmulv(b[15], (cf){-C1, -sg*S1});
    #pragma unroll
    for (int r0 = 0; r0 < 4; ++r0){
        cf u0 = b[r0], u1 = b[4+r0], u2 = b[8+r0], u3 = b[12+r0];
        cf P = padd(u0,u2), M = psub(u0,u2);
        cf Q = padd(u1,u3), R = psub(u1,u3);
        a[r0]    = padd(P,Q);
        a[r0+8]  = psub(P,Q);
        if (!INV){ a[r0+4] = paddmi(M,R); a[r0+12] = paddpi(M,R); }
        else     { a[r0+4] = paddpi(M,R); a[r0+12] = paddmi(M,R); }
    }
}

// twiddle table init: twt[lo][k] = W256^{-lo*k} (forward). 256 threads.
#define TW_INIT(twt, t)                                                   \
    {                                                                     \
        int lo_ = (t) >> 4, kk_ = (t) & 15;                               \
        float ang_ = -2.f*PI_F*(float)(lo_*kk_)/256.f;                    \
        twt[lo_][kk_] = (cf){__cosf(ang_), __sinf(ang_)};                 \
    }
#define TW_FWD(a, twt, lo)                                                \
    _Pragma("unroll")                                                     \
    for (int k_ = 1; k_ < 16; ++k_) a[k_] = cmulv(a[k_], twt[lo][k_]);
#define TW_INV(a, twt, lo)                                                \
    _Pragma("unroll")                                                     \
    for (int k_ = 1; k_ < 16; ++k_) a[k_] = cmulcv(a[k_], twt[lo][k_]);

// ---------------------------------------------------------------------------
// K1: row rfft (two-for-one), 16x16 register FFT, f16 LDS transposes,
// LDS twiddle table. grid (P_, H_/32), block 256. (unchanged R19)
// ---------------------------------------------------------------------------
__global__ void __launch_bounds__(256) k1_row_rfft(const float* __restrict__ x,
                                                   h2* __restrict__ S){
    __shared__ h2 zc[16][ZPAD];   // 16.9 KB
    __shared__ cf twt[16][17];    // 2.2 KB

    const int p = blockIdx.x, tile = blockIdx.y, t = threadIdx.x;
    const int h0 = tile * 32;
    const float* xp = x + (size_t)p*H_*W_ + (size_t)h0*W_;

    TW_INIT(twt, t)
    #pragma unroll
    for (int q = 0; q < 16; ++q)
        stz(&zc[q][t], (cf){xp[(2*q)*W_ + t], xp[(2*q+1)*W_ + t]});
    __syncthreads();

    const int q = t >> 4, lo = t & 15;
    cf a[16];
    #pragma unroll
    for (int n1 = 0; n1 < 16; ++n1) a[n1] = ldz(&zc[q][lo + 16*n1]);
    fft16r<false>(a);
    TW_FWD(a, twt, lo)
    __syncthreads();
    #pragma unroll
    for (int k0 = 0; k0 < 16; ++k0) stz(&zc[q][16*lo + (k0 ^ lo)], a[k0]);
    __syncthreads();
    #pragma unroll
    for (int n0 = 0; n0 < 16; ++n0) a[n0] = ldz(&zc[q][16*n0 + (lo ^ n0)]);
    fft16r<false>(a);
    __syncthreads();
    #pragma unroll
    for (int k1 = 0; k1 < 16; ++k1) stz(&zc[q][lo + 16*k1], a[k1]);  // natural
    __syncthreads();

    const float sc = 0.5f / 256.f;
    h2* Sp = S + (size_t)p*WF*H_;
    for (int idx = t; idx < WF*16; idx += 256){
        int kw = idx >> 4, qq = idx & 15;
        cf Z = ldz(&zc[qq][kw]);
        cf Y = ldz(&zc[qq][(256-kw)&255]);
        h4 o;
        o.x = (f16)(sc*(Z.x + Y.x));
        o.y = (f16)(sc*(Z.y - Y.y));
        o.z = (f16)(sc*(Z.y + Y.y));
        o.w = (f16)(sc*(Y.x - Z.x));
        *(h4*)&Sp[(size_t)kw*H_ + h0 + 2*qq] = o;
    }
}

// ---------------------------------------------------------------------------
// K2F: fused col-FFT + mag + conv(K=5) + sigmoid + inverse col-FFT.
// Interior tiles (1..9) take a branch-free conv path: no wrap shifts, no
// bounds checks, own-row tap from registers. grid (P_, 11), block 256.
// ---------------------------------------------------------------------------
__global__ void __launch_bounds__(256) k2f_fused(
        const h2* __restrict__ S, h2* __restrict__ D,
        h2* __restrict__ Sx, const float* __restrict__ fw,
        const float* __restrict__ fb){
    __shared__ h2 zc[16][ZPAD];           // 16.9 KB
    __shared__ f16 mag[16][272];          // 8.7 KB
    __shared__ cf twt[16][17];            // 2.2 KB
    __shared__ float cw[5];
    __shared__ float cb;

    const int p = blockIdx.x, tile = blockIdx.y, t = threadIdx.x;
    const int kw0 = tile*12;
    const int nl = min(12, WF - kw0);     // 12 (tiles 0..9) or 9 (tile 10)
    const int NL = nl + 4;                // own + 4 halo lines (<=16)
    const int c = p & (C_-1);
    const h2* Sp = S + (size_t)p*WF*H_;
    TW_INIT(twt, t)
    if (t < 5)  cw[t] = fw[c*5 + t];
    if (t == 5) cb = fb[c];

    for (int idx = t; idx < NL*128; idx += 256){
        int ll = idx >> 7, hh = (idx & 127) << 1;
        int kwa = kw0 + ll - 2;
        int phys = kwa < 0 ? kwa + WF : (kwa > 128 ? kwa - WF : kwa);
        *(h4*)&zc[ll][hh] = *(const h4*)&Sp[(size_t)phys*H_ + hh];
    }
    __syncthreads();

    const int lo = t & 15;
    const int lA = t >> 4;                // row lA holds kw = kw0+lA-2
    const bool act = lA < NL;

    cf aA[16];
    float amreg[16];                      // own-row magnitudes (registers)
    // ---- forward P1 ----
    if (act){
        #pragma unroll
        for (int n1 = 0; n1 < 16; ++n1) aA[n1] = ldz(&zc[lA][lo + 16*n1]);
        fft16r<false>(aA);
        TW_FWD(aA, twt, lo)
    }
    __syncthreads();
    if (act){
        #pragma unroll
        for (int k0 = 0; k0 < 16; ++k0) stz(&zc[lA][16*lo + (k0 ^ lo)], aA[k0]);
    }
    __syncthreads();
    // ---- forward P2 + mag ----
    if (act){
        #pragma unroll
        for (int n0 = 0; n0 < 16; ++n0) aA[n0] = ldz(&zc[lA][16*n0 + (lo ^ n0)]);
        fft16r<false>(aA);
        #pragma unroll
        for (int k1 = 0; k1 < 16; ++k1){
            amreg[k1] = sqrtf(aA[k1].x*aA[k1].x + aA[k1].y*aA[k1].y);
            mag[lA][lo + 16*k1] = (f16)amreg[k1];
        }
    }
    __syncthreads();   // mag ready

    // ---- conv(K=5) + sigmoid + inverse P1, all on registers ----
    const bool own = act && (lA >= 2) && (lA <= nl + 1);
    const bool interior = (tile >= 1) && (tile <= 9);   // wave-uniform
    if (own){
        if (interior){
            // all taps at same h, no bounds checks; own row (d=2) from regs
            #pragma unroll
            for (int k1 = 0; k1 < 16; ++k1){
                int h = lo + 16*k1;
                float acc = cb + cw[2]*amreg[k1];
                acc += (float)mag[lA-2][h] * cw[0];
                acc += (float)mag[lA-1][h] * cw[1];
                acc += (float)mag[lA+1][h] * cw[3];
                acc += (float)mag[lA+2][h] * cw[4];
                float g = 1.f + 1.f/(1.f + __expf(-acc));
                aA[k1] = aA[k1] * g;
            }
        } else {
            const int kw = kw0 + lA - 2;
            int shv[5];
            #pragma unroll
            for (int d = 0; d < 5; ++d){
                int kwa = kw + d - 2;
                shv[d] = (kwa < 0) ? -1 : (kwa > 128 ? 1 : 0);
            }
            #pragma unroll
            for (int k1 = 0; k1 < 16; ++k1){
                int h = lo + 16*k1;
                float acc = cb;
                #pragma unroll
                for (int d = 0; d < 5; ++d){
                    int h2i = h + shv[d];
                    if (h2i >= 0 && h2i < H_) acc += (float)mag[lA-2+d][h2i] * cw[d];
                }
                float g = 1.f + 1.f/(1.f + __expf(-acc));
                aA[k1] = aA[k1] * g;
            }
        }
        fft16r<true>(aA);
        TW_INV(aA, twt, lo)
    }
    __syncthreads();   // order inv-P1 writes after all fwd-P2 zc reads
    if (own){
        #pragma unroll
        for (int n0 = 0; n0 < 16; ++n0)
            stz(&zc[lA][16*lo + (n0 ^ lo)], aA[n0]);
    }
    __syncthreads();
    // ---- inverse P2 -> global ----
    const bool hI = (t >> 4) < nl;
    if (hI){
        const int lI = (t >> 4) + 2;
        #pragma unroll
        for (int k0 = 0; k0 < 16; ++k0) aA[k0] = ldz(&zc[lI][16*k0 + (lo ^ k0)]);
        fft16r<true>(aA);
        int kw = kw0 + (t >> 4);
        h2* dst = (kw < 128) ? (D + ((size_t)p*128 + kw)*H_) : (Sx + (size_t)p*H_);
        #pragma unroll
        for (int n1 = 0; n1 < 16; ++n1){
            h2 o; o.x = (f16)aA[n1].x; o.y = (f16)aA[n1].y;
            dst[lo + 16*n1] = o;
        }
    }
}

// ---------------------------------------------------------------------------
// K5: inverse row transform (Hermitian two-for-one). (unchanged R19)
// ---------------------------------------------------------------------------
__global__ void __launch_bounds__(256) k5_irow(const h2* __restrict__ D,
                                               const h2* __restrict__ Sx,
                                               f16* __restrict__ enh){
    __shared__ h2 zc[16][ZPAD];   // 16.9 KB
    __shared__ cf twt[16][17];    // 2.2 KB

    const int p = blockIdx.x, tile = blockIdx.y, t = threadIdx.x;
    const int h0 = tile * 32;
    const h2* Dp  = D  + (size_t)p*128*H_;
    const h2* Sxp = Sx + (size_t)p*H_;

    TW_INIT(twt, t)
    for (int idx = t; idx < WF*16; idx += 256){
        int kw = idx >> 4, qq = idx & 15;
        const h2* src = (kw < 128) ? (Dp + (size_t)kw*H_) : Sxp;
        h4 ab = *(const h4*)&src[h0 + 2*qq];   // A=(x,y) B=(z,w)
        float Ar = (float)ab.x, Ai = (float)ab.y;
        float Br = (float)ab.z, Bi = (float)ab.w;
        stz(&zc[qq][kw], (cf){Ar - Bi, Ai + Br});
        if (kw > 0 && kw < 128)
            stz(&zc[qq][256-kw], (cf){Ar + Bi, Br - Ai});
    }
    __syncthreads();

    const int q = t >> 4, lo = t & 15;
    cf a[16];
    #pragma unroll
    for (int k1 = 0; k1 < 16; ++k1) a[k1] = ldz(&zc[q][lo + 16*k1]);
    fft16r<true>(a);
    TW_INV(a, twt, lo)
    __syncthreads();
    #pragma unroll
    for (int n0 = 0; n0 < 16; ++n0) stz(&zc[q][16*lo + (n0 ^ lo)], a[n0]);
    __syncthreads();
    #pragma unroll
    for (int k0 = 0; k0 < 16; ++k0) a[k0] = ldz(&zc[q][16*k0 + (lo ^ k0)]);
    fft16r<true>(a);
    __syncthreads();
    #pragma unroll
    for (int n1 = 0; n1 < 16; ++n1) stz(&zc[q][lo + 16*n1], a[n1]);  // natural
    __syncthreads();

    const float inv = 1.f / 256.f;
    f16* ep = enh + (size_t)p*H_*W_ + (size_t)h0*W_;
    #pragma unroll
    for (int qq = 0; qq < 16; ++qq){
        cf v = ldz(&zc[qq][t]);
        ep[(2*qq)*W_ + t]   = (f16)(v.x * inv);
        ep[(2*qq+1)*W_ + t] = (f16)(v.y * inv);
    }
}

// ---------------------------------------------------------------------------
// K6: out = x + scale * (mix_w @ enh) via MFMA f16 16x16x32. (unchanged R19)
// ---------------------------------------------------------------------------
__global__ void __launch_bounds__(256) k6_mix(
        const float* __restrict__ x, const float* __restrict__ mixw,
        const float* __restrict__ scale, const f16* __restrict__ enh,
        float* __restrict__ out){
    __shared__ f16 Ml[64][72];

    const int b = blockIdx.x, pt = blockIdx.y, t = threadIdx.x;
    float* op = out + (size_t)b*C_*H_*W_;
    const float* xp = x + (size_t)b*C_*H_*W_;
    const f16* ep = enh + (size_t)b*C_*H_*W_;

    for (int idx = t; idx < 64*64; idx += 256){
        int o = idx >> 6, c = idx & 63;
        Ml[o][c] = (f16)mixw[idx];
    }
    __syncthreads();

    const int w  = t >> 6;
    const int l  = t & 63;
    const int lj = l & 15;
    const int lk = l >> 4;
    const int pix = pt*64 + w*16 + lj;

    f16x8 af[4][2];
    #pragma unroll
    for (int ot = 0; ot < 4; ++ot){
        #pragma unroll
        for (int kk = 0; kk < 2; ++kk)
            af[ot][kk] = *(const f16x8*)&Ml[ot*16 + lj][kk*32 + lk*8];
    }

    f32x4 acc[4];
    #pragma unroll
    for (int ot = 0; ot < 4; ++ot) acc[ot] = (f32x4){0.f, 0.f, 0.f, 0.f};

    #pragma unroll
    for (int kk = 0; kk < 2; ++kk){
        f16x8 bf;
        #pragma unroll
        for (int j = 0; j < 8; ++j)
            bf[j] = ep[(size_t)(kk*32 + lk*8 + j)*H_*W_ + pix];
        #pragma unroll
        for (int ot = 0; ot < 4; ++ot)
            acc[ot] = __builtin_amdgcn_mfma_f32_16x16x32_f16(af[ot][kk], bf, acc[ot], 0, 0, 0);
    }

    const float sc = scale[0];
    #pragma unroll
    for (int ot = 0; ot < 4; ++ot){
        #pragma unroll
        for (int r = 0; r < 4; ++r){
            int o = ot*16 + lk*4 + r;
            size_t ix = (size_t)o*H_*W_ + pix;
            op[ix] = xp[ix] + sc * acc[ot][r];
        }
    }
}

// ---------------------------------------------------------------------------
extern "C" void kernel_launch(void* const* d_in, const int* in_sizes, int n_in,
                              void* d_out, int out_size, void* d_ws, size_t ws_size,
                              hipStream_t stream){
    const float* x    = (const float*)d_in[0];
    const float* fw   = (const float*)d_in[1];
    const float* fb   = (const float*)d_in[2];
    const float* mixw = (const float*)d_in[3];
    const float* scal = (const float*)d_in[4];
    float* out = (float*)d_out;

    h2* S   = (h2*)d_ws;
    h2* Sx  = (h2*)((char*)d_ws + (size_t)P_*WF*H_*sizeof(h2));
    f16* enh = (f16*)d_ws;        // reuses S region after k2f
    h2* Dmid = (h2*)out;          // D lives in d_out mid-pipeline

    dim3 blk(256);
    k1_row_rfft <<<dim3(P_, H_/32), blk, 0, stream>>>(x, S);
    k2f_fused   <<<dim3(P_, 11),    blk, 0, stream>>>(S, Dmid, Sx, fw, fb);
    k5_irow     <<<dim3(P_, H_/32), blk, 0, stream>>>(Dmid, Sx, enh);
    k6_mix      <<<dim3(B_, 1024),  blk, 0, stream>>>(x, mixw, scal, enh, out);
}

// Round 22
// 209.077 us; speedup vs baseline: 1.1017x; 1.0252x over previous
//
#include <hip/hip_runtime.h>
#include <math.h>

#define B_ 8
#define C_ 64
#define H_ 256
#define W_ 256
#define WF 129
#define P_ (B_*C_)      // 512 planes
#define PI_F 3.14159265358979323846f
#define L2E_F 1.4426950408889634f
#define ZPAD 264        // row stride (4B units) == 8 mod 32 -> 2-way banks

typedef _Float16 f16;
struct h2 { f16 x, y; };          // 4 B
struct h4 { f16 x, y, z, w; };    // 8 B
typedef __fp16 hf2 __attribute__((ext_vector_type(2)));   // cvt_pkrtz result type
typedef _Float16 f16x8 __attribute__((ext_vector_type(8)));
typedef float f32x4 __attribute__((ext_vector_type(4)));
typedef float cf __attribute__((ext_vector_type(2)));

// packed f32->2xf16 store (v_cvt_pkrtz_f16_f32: 1 VALU instead of 2 cvt + pack)
__device__ __forceinline__ void stz(h2* p, cf v){
    *(hf2*)p = __builtin_amdgcn_cvt_pkrtz(v.x, v.y);
}
__device__ __forceinline__ cf ldz(const h2* p){ h2 v=*p; return (cf){(float)v.x,(float)v.y}; }

// ---- hand-emitted VOP3P packed-f32 complex primitives -----------------------
__device__ __forceinline__ cf padd(cf a, cf b){
    cf d; asm("v_pk_add_f32 %0, %1, %2" : "=v"(d) : "v"(a), "v"(b)); return d;
}
__device__ __forceinline__ cf psub(cf a, cf b){
    cf d; asm("v_pk_add_f32 %0, %1, %2 neg_lo:[0,1] neg_hi:[0,1]"
              : "=v"(d) : "v"(a), "v"(b)); return d;
}
// M + (-i)R = {M.x + R.y, M.y - R.x}
__device__ __forceinline__ cf paddmi(cf M, cf R){
    cf d; asm("v_pk_add_f32 %0, %1, %2 op_sel:[0,1] op_sel_hi:[1,0] neg_hi:[0,1]"
              : "=v"(d) : "v"(M), "v"(R)); return d;
}
// M + (+i)R = {M.x - R.y, M.y + R.x}
__device__ __forceinline__ cf paddpi(cf M, cf R){
    cf d; asm("v_pk_add_f32 %0, %1, %2 op_sel:[0,1] op_sel_hi:[1,0] neg_lo:[0,1]"
              : "=v"(d) : "v"(M), "v"(R)); return d;
}
// a * w : t = {a.x*w.x, a.x*w.y}; d = {-w.y*a.y + t.x, w.x*a.y + t.y}
__device__ __forceinline__ cf cmulv(cf a, cf w){
    cf t, d;
    asm("v_pk_mul_f32 %0, %1, %2 op_sel_hi:[0,1]" : "=v"(t) : "v"(a), "v"(w));
    asm("v_pk_fma_f32 %0, %1, %2, %3 op_sel:[1,1,0] op_sel_hi:[1,0,1] neg_lo:[0,1,0]"
        : "=v"(d) : "v"(a), "v"(w), "v"(t));
    return d;
}
// a * conj(w): t = {a.x*w.x, a.y*w.x}; d = {a.y*w.y + t.x, -a.x*w.y + t.y}
__device__ __forceinline__ cf cmulcv(cf a, cf w){
    cf t, d;
    asm("v_pk_mul_f32 %0, %1, %2 op_sel_hi:[1,0]" : "=v"(t) : "v"(a), "v"(w));
    asm("v_pk_fma_f32 %0, %1, %2, %3 op_sel:[1,1,0] op_sel_hi:[0,1,1] neg_hi:[1,0,0]"
        : "=v"(d) : "v"(a), "v"(w), "v"(t));
    return d;
}
// a * scalar g (packed)
__device__ __forceinline__ cf pscale(cf a, float g){
    cf gg = (cf){g, g};
    cf d; asm("v_pk_mul_f32 %0, %1, %2" : "=v"(d) : "v"(a), "v"(gg)); return d;
}

// full 16-point FFT in registers; radix-4 x 2, constant W16 twiddles.
template<bool INV>
__device__ __forceinline__ void fft16r(cf* a){
    const float C1 = 0.92387953251128674f;
    const float S1 = 0.38268343236508978f;
    const float R2 = 0.70710678118654752f;
    cf b[16];
    #pragma unroll
    for (int m0 = 0; m0 < 4; ++m0){
        cf u0 = a[m0], u1 = a[m0+4], u2 = a[m0+8], u3 = a[m0+12];
        cf P = padd(u0,u2), M = psub(u0,u2);
        cf Q = padd(u1,u3), R = psub(u1,u3);
        b[m0*4+0] = padd(P,Q);
        b[m0*4+2] = psub(P,Q);
        if (!INV){ b[m0*4+1] = paddmi(M,R); b[m0*4+3] = paddpi(M,R); }
        else     { b[m0*4+1] = paddpi(M,R); b[m0*4+3] = paddmi(M,R); }
    }
    const float sg = INV ? 1.f : -1.f;
    b[5]  = cmulv(b[5],  (cf){C1,  sg*S1});
    b[6]  = cmulv(b[6],  (cf){R2,  sg*R2});
    b[7]  = cmulv(b[7],  (cf){S1,  sg*C1});
    b[9]  = cmulv(b[9],  (cf){R2,  sg*R2});
    b[10] = cmulv(b[10], (cf){0.f, sg*1.f});
    b[11] = cmulv(b[11], (cf){-R2, sg*R2});
    b[13] = cmulv(b[13], (cf){S1,  sg*C1});
    b[14] = cmulv(b[14], (cf){-R2, sg*R2});
    b[15] = cmulv(b[15], (cf){-C1, -sg*S1});
    #pragma unroll
    for (int r0 = 0; r0 < 4; ++r0){
        cf u0 = b[r0], u1 = b[4+r0], u2 = b[8+r0], u3 = b[12+r0];
        cf P = padd(u0,u2), M = psub(u0,u2);
        cf Q = padd(u1,u3), R = psub(u1,u3);
        a[r0]    = padd(P,Q);
        a[r0+8]  = psub(P,Q);
        if (!INV){ a[r0+4] = paddmi(M,R); a[r0+12] = paddpi(M,R); }
        else     { a[r0+4] = paddpi(M,R); a[r0+12] = paddmi(M,R); }
    }
}

// twiddle table init: twt[lo][k] = W256^{-lo*k} (forward). 256 threads.
#define TW_INIT(twt, t)                                                   \
    {                                                                     \
        int lo_ = (t) >> 4, kk_ = (t) & 15;                               \
        float ang_ = -2.f*PI_F*(float)(lo_*kk_)/256.f;                    \
        twt[lo_][kk_] = (cf){__cosf(ang_), __sinf(ang_)};                 \
    }
#define TW_FWD(a, twt, lo)                                                \
    _Pragma("unroll")                                                     \
    for (int k_ = 1; k_ < 16; ++k_) a[k_] = cmulv(a[k_], twt[lo][k_]);
#define TW_INV(a, twt, lo)                                                \
    _Pragma("unroll")                                                     \
    for (int k_ = 1; k_ < 16; ++k_) a[k_] = cmulcv(a[k_], twt[lo][k_]);

// ---------------------------------------------------------------------------
// K1: row rfft (two-for-one), 16x16 register FFT, f16 LDS transposes,
// LDS twiddle table, pkrtz stores. grid (P_, H_/32), block 256.
// ---------------------------------------------------------------------------
__global__ void __launch_bounds__(256) k1_row_rfft(const float* __restrict__ x,
                                                   h2* __restrict__ S){
    __shared__ h2 zc[16][ZPAD];   // 16.9 KB
    __shared__ cf twt[16][17];    // 2.2 KB

    const int p = blockIdx.x, tile = blockIdx.y, t = threadIdx.x;
    const int h0 = tile * 32;
    const float* xp = x + (size_t)p*H_*W_ + (size_t)h0*W_;

    TW_INIT(twt, t)
    #pragma unroll
    for (int q = 0; q < 16; ++q)
        stz(&zc[q][t], (cf){xp[(2*q)*W_ + t], xp[(2*q+1)*W_ + t]});
    __syncthreads();

    const int q = t >> 4, lo = t & 15;
    cf a[16];
    #pragma unroll
    for (int n1 = 0; n1 < 16; ++n1) a[n1] = ldz(&zc[q][lo + 16*n1]);
    fft16r<false>(a);
    TW_FWD(a, twt, lo)
    __syncthreads();
    #pragma unroll
    for (int k0 = 0; k0 < 16; ++k0) stz(&zc[q][16*lo + (k0 ^ lo)], a[k0]);
    __syncthreads();
    #pragma unroll
    for (int n0 = 0; n0 < 16; ++n0) a[n0] = ldz(&zc[q][16*n0 + (lo ^ n0)]);
    fft16r<false>(a);
    __syncthreads();
    #pragma unroll
    for (int k1 = 0; k1 < 16; ++k1) stz(&zc[q][lo + 16*k1], a[k1]);  // natural
    __syncthreads();

    const float sc = 0.5f / 256.f;
    h2* Sp = S + (size_t)p*WF*H_;
    for (int idx = t; idx < WF*16; idx += 256){
        int kw = idx >> 4, qq = idx & 15;
        cf Z = ldz(&zc[qq][kw]);
        cf Y = ldz(&zc[qq][(256-kw)&255]);
        hf2 oa = __builtin_amdgcn_cvt_pkrtz(sc*(Z.x + Y.x), sc*(Z.y - Y.y));
        hf2 ob = __builtin_amdgcn_cvt_pkrtz(sc*(Z.y + Y.y), sc*(Y.x - Z.x));
        hf2* dst = (hf2*)&Sp[(size_t)kw*H_ + h0 + 2*qq];
        dst[0] = oa;   // A (row 2qq)
        dst[1] = ob;   // B (row 2qq+1)
    }
}

// ---------------------------------------------------------------------------
// K2F: fused col-FFT + mag + conv(K=5) + sigmoid + inverse col-FFT.
// Interior tiles branch-free conv; exp2-scaled weights; pkrtz stores.
// grid (P_, 11), block 256.
// ---------------------------------------------------------------------------
__global__ void __launch_bounds__(256) k2f_fused(
        const h2* __restrict__ S, h2* __restrict__ D,
        h2* __restrict__ Sx, const float* __restrict__ fw,
        const float* __restrict__ fb){
    __shared__ h2 zc[16][ZPAD];           // 16.9 KB
    __shared__ f16 mag[16][272];          // 8.7 KB
    __shared__ cf twt[16][17];            // 2.2 KB
    __shared__ float cw[5];
    __shared__ float cb;

    const int p = blockIdx.x, tile = blockIdx.y, t = threadIdx.x;
    const int kw0 = tile*12;
    const int nl = min(12, WF - kw0);     // 12 (tiles 0..9) or 9 (tile 10)
    const int NL = nl + 4;                // own + 4 halo lines (<=16)
    const int c = p & (C_-1);
    const h2* Sp = S + (size_t)p*WF*H_;
    TW_INIT(twt, t)
    // weights pre-scaled by log2(e): sigmoid via exp2 (saves a v_mul per use)
    if (t < 5)  cw[t] = fw[c*5 + t] * L2E_F;
    if (t == 5) cb = fb[c] * L2E_F;

    for (int idx = t; idx < NL*128; idx += 256){
        int ll = idx >> 7, hh = (idx & 127) << 1;
        int kwa = kw0 + ll - 2;
        int phys = kwa < 0 ? kwa + WF : (kwa > 128 ? kwa - WF : kwa);
        *(h4*)&zc[ll][hh] = *(const h4*)&Sp[(size_t)phys*H_ + hh];
    }
    __syncthreads();

    const int lo = t & 15;
    const int lA = t >> 4;                // row lA holds kw = kw0+lA-2
    const bool act = lA < NL;

    cf aA[16];
    float amreg[16];                      // own-row magnitudes (registers)
    // ---- forward P1 ----
    if (act){
        #pragma unroll
        for (int n1 = 0; n1 < 16; ++n1) aA[n1] = ldz(&zc[lA][lo + 16*n1]);
        fft16r<false>(aA);
        TW_FWD(aA, twt, lo)
    }
    __syncthreads();
    if (act){
        #pragma unroll
        for (int k0 = 0; k0 < 16; ++k0) stz(&zc[lA][16*lo + (k0 ^ lo)], aA[k0]);
    }
    __syncthreads();
    // ---- forward P2 + mag ----
    if (act){
        #pragma unroll
        for (int n0 = 0; n0 < 16; ++n0) aA[n0] = ldz(&zc[lA][16*n0 + (lo ^ n0)]);
        fft16r<false>(aA);
        #pragma unroll
        for (int k1 = 0; k1 < 16; ++k1){
            amreg[k1] = sqrtf(aA[k1].x*aA[k1].x + aA[k1].y*aA[k1].y);
            mag[lA][lo + 16*k1] = (f16)amreg[k1];
        }
    }
    __syncthreads();   // mag ready

    // ---- conv(K=5) + sigmoid + inverse P1, all on registers ----
    const bool own = act && (lA >= 2) && (lA <= nl + 1);
    const bool interior = (tile >= 1) && (tile <= 9);   // wave-uniform
    if (own){
        if (interior){
            #pragma unroll
            for (int k1 = 0; k1 < 16; ++k1){
                int h = lo + 16*k1;
                float acc = cb + cw[2]*amreg[k1];
                acc += (float)mag[lA-2][h] * cw[0];
                acc += (float)mag[lA-1][h] * cw[1];
                acc += (float)mag[lA+1][h] * cw[3];
                acc += (float)mag[lA+2][h] * cw[4];
                float g = 1.f + 1.f/(1.f + exp2f(-acc));
                aA[k1] = pscale(aA[k1], g);
            }
        } else {
            const int kw = kw0 + lA - 2;
            int shv[5];
            #pragma unroll
            for (int d = 0; d < 5; ++d){
                int kwa = kw + d - 2;
                shv[d] = (kwa < 0) ? -1 : (kwa > 128 ? 1 : 0);
            }
            #pragma unroll
            for (int k1 = 0; k1 < 16; ++k1){
                int h = lo + 16*k1;
                float acc = cb;
                #pragma unroll
                for (int d = 0; d < 5; ++d){
                    int h2i = h + shv[d];
                    if (h2i >= 0 && h2i < H_) acc += (float)mag[lA-2+d][h2i] * cw[d];
                }
                float g = 1.f + 1.f/(1.f + exp2f(-acc));
                aA[k1] = pscale(aA[k1], g);
            }
        }
        fft16r<true>(aA);
        TW_INV(aA, twt, lo)
    }
    __syncthreads();   // order inv-P1 writes after all fwd-P2 zc reads
    if (own){
        #pragma unroll
        for (int n0 = 0; n0 < 16; ++n0)
            stz(&zc[lA][16*lo + (n0 ^ lo)], aA[n0]);
    }
    __syncthreads();
    // ---- inverse P2 -> global ----
    const bool hI = (t >> 4) < nl;
    if (hI){
        const int lI = (t >> 4) + 2;
        #pragma unroll
        for (int k0 = 0; k0 < 16; ++k0) aA[k0] = ldz(&zc[lI][16*k0 + (lo ^ k0)]);
        fft16r<true>(aA);
        int kw = kw0 + (t >> 4);
        h2* dst = (kw < 128) ? (D + ((size_t)p*128 + kw)*H_) : (Sx + (size_t)p*H_);
        #pragma unroll
        for (int n1 = 0; n1 < 16; ++n1)
            *(hf2*)&dst[lo + 16*n1] = __builtin_amdgcn_cvt_pkrtz(aA[n1].x, aA[n1].y);
    }
}

// ---------------------------------------------------------------------------
// K5: inverse row transform (Hermitian two-for-one), pkrtz stores.
// grid (P_, H_/32), block 256.
// ---------------------------------------------------------------------------
__global__ void __launch_bounds__(256) k5_irow(const h2* __restrict__ D,
                                               const h2* __restrict__ Sx,
                                               f16* __restrict__ enh){
    __shared__ h2 zc[16][ZPAD];   // 16.9 KB
    __shared__ cf twt[16][17];    // 2.2 KB

    const int p = blockIdx.x, tile = blockIdx.y, t = threadIdx.x;
    const int h0 = tile * 32;
    const h2* Dp  = D  + (size_t)p*128*H_;
    const h2* Sxp = Sx + (size_t)p*H_;

    TW_INIT(twt, t)
    for (int idx = t; idx < WF*16; idx += 256){
        int kw = idx >> 4, qq = idx & 15;
        const h2* src = (kw < 128) ? (Dp + (size_t)kw*H_) : Sxp;
        h4 ab = *(const h4*)&src[h0 + 2*qq];   // A=(x,y) B=(z,w)
        float Ar = (float)ab.x, Ai = (float)ab.y;
        float Br = (float)ab.z, Bi = (float)ab.w;
        stz(&zc[qq][kw], (cf){Ar - Bi, Ai + Br});
        if (kw > 0 && kw < 128)
            stz(&zc[qq][256-kw], (cf){Ar + Bi, Br - Ai});
    }
    __syncthreads();

    const int q = t >> 4, lo = t & 15;
    cf a[16];
    #pragma unroll
    for (int k1 = 0; k1 < 16; ++k1) a[k1] = ldz(&zc[q][lo + 16*k1]);
    fft16r<true>(a);
    TW_INV(a, twt, lo)
    __syncthreads();
    #pragma unroll
    for (int n0 = 0; n0 < 16; ++n0) stz(&zc[q][16*lo + (n0 ^ lo)], a[n0]);
    __syncthreads();
    #pragma unroll
    for (int k0 = 0; k0 < 16; ++k0) a[k0] = ldz(&zc[q][16*k0 + (lo ^ k0)]);
    fft16r<true>(a);
    __syncthreads();
    #pragma unroll
    for (int n1 = 0; n1 < 16; ++n1) stz(&zc[q][lo + 16*n1], a[n1]);  // natural
    __syncthreads();

    const float inv = 1.f / 256.f;
    f16* ep = enh + (size_t)p*H_*W_ + (size_t)h0*W_;
    #pragma unroll
    for (int qq = 0; qq < 16; ++qq){
        cf v = ldz(&zc[qq][t]);
        ep[(2*qq)*W_ + t]   = (f16)(v.x * inv);
        ep[(2*qq+1)*W_ + t] = (f16)(v.y * inv);
    }
}

// ---------------------------------------------------------------------------
// K6: out = x + scale * (mix_w @ enh) via MFMA f16 16x16x32. (unchanged)
// ---------------------------------------------------------------------------
__global__ void __launch_bounds__(256) k6_mix(
        const float* __restrict__ x, const float* __restrict__ mixw,
        const float* __restrict__ scale, const f16* __restrict__ enh,
        float* __restrict__ out){
    __shared__ f16 Ml[64][72];

    const int b = blockIdx.x, pt = blockIdx.y, t = threadIdx.x;
    float* op = out + (size_t)b*C_*H_*W_;
    const float* xp = x + (size_t)b*C_*H_*W_;
    const f16* ep = enh + (size_t)b*C_*H_*W_;

    for (int idx = t; idx < 64*64; idx += 256){
        int o = idx >> 6, c = idx & 63;
        Ml[o][c] = (f16)mixw[idx];
    }
    __syncthreads();

    const int w  = t >> 6;
    const int l  = t & 63;
    const int lj = l & 15;
    const int lk = l >> 4;
    const int pix = pt*64 + w*16 + lj;

    f16x8 af[4][2];
    #pragma unroll
    for (int ot = 0; ot < 4; ++ot){
        #pragma unroll
        for (int kk = 0; kk < 2; ++kk)
            af[ot][kk] = *(const f16x8*)&Ml[ot*16 + lj][kk*32 + lk*8];
    }

    f32x4 acc[4];
    #pragma unroll
    for (int ot = 0; ot < 4; ++ot) acc[ot] = (f32x4){0.f, 0.f, 0.f, 0.f};

    #pragma unroll
    for (int kk = 0; kk < 2; ++kk){
        f16x8 bf;
        #pragma unroll
        for (int j = 0; j < 8; ++j)
            bf[j] = ep[(size_t)(kk*32 + lk*8 + j)*H_*W_ + pix];
        #pragma unroll
        for (int ot = 0; ot < 4; ++ot)
            acc[ot] = __builtin_amdgcn_mfma_f32_16x16x32_f16(af[ot][kk], bf, acc[ot], 0, 0, 0);
    }

    const float sc = scale[0];
    #pragma unroll
    for (int ot = 0; ot < 4; ++ot){
        #pragma unroll
        for (int r = 0; r < 4; ++r){
            int o = ot*16 + lk*4 + r;
            size_t ix = (size_t)o*H_*W_ + pix;
            op[ix] = xp[ix] + sc * acc[ot][r];
        }
    }
}

// ---------------------------------------------------------------------------
extern "C" void kernel_launch(void* const* d_in, const int* in_sizes, int n_in,
                              void* d_out, int out_size, void* d_ws, size_t ws_size,
                              hipStream_t stream){
    const float* x    = (const float*)d_in[0];
    const float* fw   = (const float*)d_in[1];
    const float* fb   = (const float*)d_in[2];
    const float* mixw = (const float*)d_in[3];
    const float* scal = (const float*)d_in[4];
    float* out = (float*)d_out;

    h2* S   = (h2*)d_ws;
    h2* Sx  = (h2*)((char*)d_ws + (size_t)P_*WF*H_*sizeof(h2));
    f16* enh = (f16*)d_ws;        // reuses S region after k2f
    h2* Dmid = (h2*)out;          // D lives in d_out mid-pipeline

    dim3 blk(256);
    k1_row_rfft <<<dim3(P_, H_/32), blk, 0, stream>>>(x, S);
    k2f_fused   <<<dim3(P_, 11),    blk, 0, stream>>>(S, Dmid, Sx, fw, fb);
    k5_irow     <<<dim3(P_, H_/32), blk, 0, stream>>>(Dmid, Sx, enh);
    k6_mix      <<<dim3(B_, 1024),  blk, 0, stream>>>(x, mixw, scal, enh, out);
}